// Round 8
// baseline (1394.719 us; speedup 1.0000x reference)
//
#include <hip/hip_runtime.h>
#include <stdint.h>

#define B_SZ   4096
#define IN_SZ  1024
#define NE     8
#define NC     1000
#define HIDE   16384   // HID*E
#define OUTE   1024    // OUT per expert
#define GEPS   1e-6f
#define NSPLIT 2
#define KSPL   8192    // HIDE / NSPLIT
#define MTT    6       // moe m-tiles per expert (256 rows each; gn<=1536 guaranteed)

typedef __attribute__((ext_vector_type(8))) short short8;
typedef __attribute__((ext_vector_type(4))) float floatx4;

__device__ __forceinline__ unsigned short f2bf(float f) {
    unsigned u = __float_as_uint(f);
    u += 0x7fffu + ((u >> 16) & 1u);
    return (unsigned short)(u >> 16);
}
__device__ __forceinline__ float bf2f(unsigned short h) {
    return __uint_as_float(((unsigned)h) << 16);
}

__device__ __forceinline__ void async16(const void* g, void* l) {
    __builtin_amdgcn_global_load_lds(
        (const __attribute__((address_space(1))) void*)g,
        (__attribute__((address_space(3))) void*)l, 16, 0, 0);
}

// ---------------- conversion fp32 -> bf16 ---------------------------------------
__global__ __launch_bounds__(256) void k_cvt(const float* __restrict__ src,
                                             unsigned short* __restrict__ dst, int n) {
    int i = (blockIdx.x * 256 + threadIdx.x) * 4;
    int stride = gridDim.x * 256 * 4;
    for (; i < n; i += stride) {
        float4 v = *(const float4*)(src + i);
        ushort4 o;
        o.x = f2bf(v.x); o.y = f2bf(v.y); o.z = f2bf(v.z); o.w = f2bf(v.w);
        *(ushort4*)(dst + i) = o;
    }
}

// ---------------- gating (fp32 exact) -------------------------------------------
__global__ __launch_bounds__(256) void k_gate(const float* __restrict__ x,
                                              const float* __restrict__ Wg,
                                              const float* __restrict__ bg,
                                              float* __restrict__ logits,
                                              float* __restrict__ Gx) {
    int wid = threadIdx.x >> 6, lane = threadIdx.x & 63;
    int b = blockIdx.x * 4 + wid;
    const float* xr = x + (size_t)b * IN_SZ;
    float xv[16];
#pragma unroll
    for (int t = 0; t < 16; ++t) xv[t] = xr[lane + 64 * t];
    float lg[NE];
#pragma unroll
    for (int e = 0; e < NE; ++e) {
        const float* wr = Wg + e * IN_SZ;
        float s = 0.f;
#pragma unroll
        for (int t = 0; t < 16; ++t) s += xv[t] * wr[lane + 64 * t];
#pragma unroll
        for (int m = 32; m >= 1; m >>= 1) s += __shfl_xor(s, m, 64);
        lg[e] = s + bg[e];
    }
    if (lane == 0) {
        float ss = 0.f;
#pragma unroll
        for (int e = 0; e < NE; ++e) { logits[b * NE + e] = lg[e]; ss += lg[e] * lg[e]; }
        Gx[b] = sqrtf(ss);
    }
}

__global__ __launch_bounds__(1024) void k_gsum(const float* __restrict__ Gx, float* __restrict__ gsum) {
    __shared__ float sm[1024];
    int t = threadIdx.x;
    sm[t] = Gx[t] + Gx[t + 1024] + Gx[t + 2048] + Gx[t + 3072];
    __syncthreads();
    for (int m = 512; m >= 1; m >>= 1) {
        if (t < m) sm[t] += sm[t + m];
        __syncthreads();
    }
    if (t == 0) gsum[0] = sm[0];
}

__global__ void k_zeroctrl(int* ctrl) {
    if (threadIdx.x < 24) ctrl[threadIdx.x] = 0;
}

__global__ __launch_bounds__(256) void k_topk(const float* __restrict__ logits,
                                              const float* __restrict__ Gx,
                                              const float* __restrict__ gsum,
                                              const float* __restrict__ gamma,
                                              const float* __restrict__ beta,
                                              int* __restrict__ tidx, float* __restrict__ tp,
                                              int* __restrict__ counts) {
    int b = blockIdx.x * 256 + threadIdx.x;
    float nx = Gx[b] / (gsum[0] * (1.0f / (float)B_SZ) + GEPS);
    float l[NE];
    float mx = -1e30f;
#pragma unroll
    for (int e = 0; e < NE; ++e) {
        l[e] = gamma[e] * (logits[b * NE + e] * nx) + beta[e];
        mx = fmaxf(mx, l[e]);
    }
    float se = 0.f;
#pragma unroll
    for (int e = 0; e < NE; ++e) { l[e] = expf(l[e] - mx); se += l[e]; }
    float inv = 1.f / se;
    int i0 = 0; float p0 = l[0];
#pragma unroll
    for (int e = 1; e < NE; ++e) if (l[e] > p0) { p0 = l[e]; i0 = e; }
    int i1 = -1; float p1 = -1.f;
#pragma unroll
    for (int e = 0; e < NE; ++e) if (e != i0 && l[e] > p1) { p1 = l[e]; i1 = e; }
    tidx[b * 2 + 0] = i0; tidx[b * 2 + 1] = i1;
    tp[b * 2 + 0] = p0 * inv; tp[b * 2 + 1] = p1 * inv;
    atomicAdd(&counts[i0], 1);
    atomicAdd(&counts[i1], 1);
}

__global__ void k_offsets(const int* __restrict__ counts, int* __restrict__ offs) {
    if (threadIdx.x == 0) {
        int a = 0;
        for (int e = 0; e < NE; ++e) { offs[e] = a; a += counts[e]; }
    }
}

__global__ __launch_bounds__(256) void k_fill(const int* __restrict__ tidx, const float* __restrict__ tp,
                                              const int* __restrict__ offs, int* __restrict__ cursors,
                                              int* __restrict__ rowsw, int* __restrict__ slotof) {
    int b = blockIdx.x * 256 + threadIdx.x;
#pragma unroll
    for (int k = 0; k < 2; ++k) {
        int e = tidx[b * 2 + k];
        int pos = atomicAdd(&cursors[e], 1);
        int at = offs[e] + pos;
        rowsw[at] = b * 2 + k;
        slotof[b * 2 + k] = at;
    }
}

// ============ 256x256 / BK=64 core, 8 waves (2x4), wave tile 128x64 =============
// LDS per buffer (64KB): A 256x64 (32KB) | B 256x64 (32KB); dbuf = 128KB.
// LDS[r][slot] holds global chunk slot^(r&7) (16B chunks); pre-swizzled source
// + swizzled ds_read; row&7 == lane&7 identity (verified 0-conflict r5-r7).
// Drain discipline (round-6 proven): stage(buf^1,t+1) -> compute(buf) ->
// __syncthreads (vmcnt(0)+barrier) -> flip. Raises FLOP/LDS-byte 1.33x over
// the 64x64-wave-tile core (the measured 41%-cap bottleneck).

__device__ __forceinline__ void stage256(const unsigned short* const* pa,
                                         const unsigned short* const* pb,
                                         char* bufc, int koff, int tid) {
#pragma unroll
    for (int c = 0; c < 4; ++c)
        async16(pa[c] + koff, bufc + c * 8192 + tid * 16);
#pragma unroll
    for (int c = 0; c < 4; ++c)
        async16(pb[c] + koff, bufc + 32768 + c * 8192 + tid * 16);
}

__device__ __forceinline__ void compute256(const short* buf, const int* aoff, const int* boff,
                                           floatx4 acc[8][4]) {
    const short* sA = buf;
    const short* sB = buf + 16384;
    short8 av[8], bv[4];
    // khalf 0
#pragma unroll
    for (int i = 0; i < 8; ++i) av[i] = *(const short8*)(sA + aoff[i]);
#pragma unroll
    for (int j = 0; j < 4; ++j) bv[j] = *(const short8*)(sB + boff[j]);
    asm volatile("s_waitcnt lgkmcnt(0)" ::: "memory");
    __builtin_amdgcn_sched_barrier(0);
    __builtin_amdgcn_s_setprio(1);
#pragma unroll
    for (int i = 0; i < 8; ++i)
#pragma unroll
        for (int j = 0; j < 4; ++j)
            acc[i][j] = __builtin_amdgcn_mfma_f32_16x16x32_bf16(av[i], bv[j], acc[i][j], 0, 0, 0);
    __builtin_amdgcn_s_setprio(0);
    // khalf 1 (slot^4 -> shorts ^32)
#pragma unroll
    for (int i = 0; i < 8; ++i) av[i] = *(const short8*)(sA + (aoff[i] ^ 32));
#pragma unroll
    for (int j = 0; j < 4; ++j) bv[j] = *(const short8*)(sB + (boff[j] ^ 32));
    asm volatile("s_waitcnt lgkmcnt(0)" ::: "memory");
    __builtin_amdgcn_sched_barrier(0);
    __builtin_amdgcn_s_setprio(1);
#pragma unroll
    for (int i = 0; i < 8; ++i)
#pragma unroll
        for (int j = 0; j < 4; ++j)
            acc[i][j] = __builtin_amdgcn_mfma_f32_16x16x32_bf16(av[i], bv[j], acc[i][j], 0, 0, 0);
    __builtin_amdgcn_s_setprio(0);
}

// nkt even. smem = 131072B dynamic.
__device__ __forceinline__ void core256(const unsigned short* const* pa,
                                        const unsigned short* const* pb,
                                        short* smem, int nkt, int wm, int wn,
                                        int tid, int lane, floatx4 acc[8][4]) {
    char* b0c = (char*)smem;
    char* b1c = b0c + 65536;
    const int sl = ((lane >> 4) ^ (lane & 7)) * 8;
    int aoff[8], boff[4];
#pragma unroll
    for (int i = 0; i < 8; ++i)
        aoff[i] = (wm * 128 + i * 16 + (lane & 15)) * 64 + sl;
#pragma unroll
    for (int j = 0; j < 4; ++j)
        boff[j] = (wn * 64 + j * 16 + (lane & 15)) * 64 + sl;
    stage256(pa, pb, b0c, 0, tid);
    __syncthreads();
#pragma unroll 1
    for (int kt = 0; kt < nkt; kt += 2) {
        if (kt + 1 < nkt) stage256(pa, pb, b1c, (kt + 1) * 64, tid);
        compute256(smem, aoff, boff, acc);
        __syncthreads();
        if (kt + 2 < nkt) stage256(pa, pb, b0c, (kt + 2) * 64, tid);
        compute256(smem + 32768, aoff, boff, acc);
        __syncthreads();
    }
}

// GEMM1: h = relu(x @ W1^T + b1)  [4096,1024] x [16384,1024]^T -> bf16 [4096,16384]
__global__ __launch_bounds__(512, 1) void k_h8(const unsigned short* __restrict__ xb,
                                               const unsigned short* __restrict__ w1b,
                                               const float* __restrict__ b1,
                                               unsigned short* __restrict__ hout) {
    extern __shared__ short smem[];
    const int tid = threadIdx.x, lane = tid & 63, w = tid >> 6;
    const int wm = w >> 2, wn = w & 3;
    // bijective XCD swizzle (grid 1024): same-XCD neighbors share nt (B-panel)
    const int wg = (blockIdx.x & 7) * (gridDim.x >> 3) + (blockIdx.x >> 3);
    const int mt = wg & 15, nt = wg >> 4;
    const int m0 = mt * 256, n0 = nt * 256;
    const int srow = tid >> 3;                     // 0..63
    const int cswz = ((tid & 7) ^ (srow & 7)) * 8; // pre-swizzled source chunk
    const unsigned short* pa[4];
    const unsigned short* pb[4];
#pragma unroll
    for (int c = 0; c < 4; ++c) {
        pa[c] = xb  + (size_t)(m0 + 64 * c + srow) * IN_SZ + cswz;
        pb[c] = w1b + (size_t)(n0 + 64 * c + srow) * IN_SZ + cswz;
    }
    floatx4 acc[8][4] = {};
    core256(pa, pb, smem, IN_SZ / 64, wm, wn, tid, lane, acc);
#pragma unroll
    for (int i = 0; i < 8; ++i)
#pragma unroll
        for (int j = 0; j < 4; ++j)
#pragma unroll
            for (int r = 0; r < 4; ++r) {
                int row = m0 + wm * 128 + i * 16 + (lane >> 4) * 4 + r;
                int col = n0 + wn * 64 + j * 16 + (lane & 15);
                float v = acc[i][j][r] + b1[col];
                hout[(size_t)row * HIDE + col] = f2bf(fmaxf(v, 0.f));
            }
}

// GEMM2 grouped, split-K=2: gathered h rows x W2 expert slice -> bf16 partials
__global__ __launch_bounds__(512, 1) void k_moe(const unsigned short* __restrict__ h,
                                                const unsigned short* __restrict__ w2b,
                                                const int* __restrict__ counts,
                                                const int* __restrict__ offs,
                                                const int* __restrict__ rowsw,
                                                unsigned short* __restrict__ parts) {
    // grid 384 = 8e x 2sp x 4nt x 6mt; mt innermost -> same-XCD share B-panel
    const int wg = (blockIdx.x & 7) * (gridDim.x >> 3) + (blockIdx.x >> 3);
    const int mt = wg % MTT;
    const int r2 = wg / MTT;
    const int nt = r2 & 3, sp = (r2 >> 2) & 1, e = r2 >> 3;
    const int gn = counts[e];
    if (mt * 256 >= gn) return;
    const int gbase = offs[e];
    extern __shared__ short smem[];
    const int tid = threadIdx.x, lane = tid & 63, w = tid >> 6;
    const int wm = w >> 2, wn = w & 3;
    const int srow = tid >> 3;
    const int cswz = ((tid & 7) ^ (srow & 7)) * 8;
    const unsigned short* pa[4];
    const unsigned short* pb[4];
#pragma unroll
    for (int c = 0; c < 4; ++c) {
        int lr = mt * 256 + 64 * c + srow;
        if (lr > gn - 1) lr = gn - 1;
        int grow = rowsw[gbase + lr] >> 1;
        pa[c] = h + (size_t)grow * HIDE + sp * KSPL + cswz;
        pb[c] = w2b + (size_t)(e * OUTE + nt * 256 + 64 * c + srow) * HIDE + sp * KSPL + cswz;
    }
    floatx4 acc[8][4] = {};
    core256(pa, pb, smem, KSPL / 64, wm, wn, tid, lane, acc);
    unsigned short* pbase = parts + (size_t)sp * B_SZ * 2 * OUTE;
#pragma unroll
    for (int i = 0; i < 8; ++i)
#pragma unroll
        for (int j = 0; j < 4; ++j)
#pragma unroll
            for (int r = 0; r < 4; ++r) {
                int lr = mt * 256 + wm * 128 + i * 16 + (lane >> 4) * 4 + r;
                if (lr < gn) {
                    int at = gbase + lr;
                    int col = nt * 256 + wn * 64 + j * 16 + (lane & 15);
                    pbase[(size_t)at * OUTE + col] = f2bf(acc[i][j][r]);
                }
            }
}

// reduce: ymix[b] = sum_k tp[b,k] * (sum_sp parts[sp][slot(b,k)] + b2[e_k])
__global__ __launch_bounds__(256) void k_reduce(const unsigned short* __restrict__ parts,
                                                const int* __restrict__ slotof,
                                                const int* __restrict__ tidx,
                                                const float* __restrict__ tp,
                                                const float* __restrict__ b2,
                                                unsigned short* __restrict__ ymix) {
    int i = blockIdx.x * 256 + threadIdx.x;   // B_SZ * 256 threads, 4 cols each
    int b = i >> 8, col = (i & 255) * 4;
    int at0 = slotof[b * 2], at1 = slotof[b * 2 + 1];
    int e0 = tidx[b * 2], e1 = tidx[b * 2 + 1];
    float q0 = tp[b * 2], q1 = tp[b * 2 + 1];
    float y0[4] = {0.f, 0.f, 0.f, 0.f}, y1[4] = {0.f, 0.f, 0.f, 0.f};
#pragma unroll
    for (int sp = 0; sp < NSPLIT; ++sp) {
        ushort4 u0 = *(const ushort4*)(parts + ((size_t)sp * B_SZ * 2 + at0) * OUTE + col);
        ushort4 u1 = *(const ushort4*)(parts + ((size_t)sp * B_SZ * 2 + at1) * OUTE + col);
        y0[0] += bf2f(u0.x); y0[1] += bf2f(u0.y); y0[2] += bf2f(u0.z); y0[3] += bf2f(u0.w);
        y1[0] += bf2f(u1.x); y1[1] += bf2f(u1.y); y1[2] += bf2f(u1.z); y1[3] += bf2f(u1.w);
    }
    float4 bb0 = *(const float4*)(b2 + (size_t)e0 * OUTE + col);
    float4 bb1 = *(const float4*)(b2 + (size_t)e1 * OUTE + col);
    ushort4 o;
    o.x = f2bf(q0 * (y0[0] + bb0.x) + q1 * (y1[0] + bb1.x));
    o.y = f2bf(q0 * (y0[1] + bb0.y) + q1 * (y1[1] + bb1.y));
    o.z = f2bf(q0 * (y0[2] + bb0.z) + q1 * (y1[2] + bb1.z));
    o.w = f2bf(q0 * (y0[3] + bb0.w) + q1 * (y1[3] + bb1.w));
    *(ushort4*)(ymix + (size_t)b * OUTE + col) = o;
}

// ---------------- 128x128 / BK=64 dbuf core (round-6/7 proven; final GEMM) -----
__device__ __forceinline__ void stage_bk64(const unsigned short* const* pa,
                                           const unsigned short* const* pb,
                                           char* bufc, int koff, int tid) {
#pragma unroll
    for (int c = 0; c < 4; ++c) {
        async16(pa[c] + koff, bufc + c * 4096 + tid * 16);
        async16(pb[c] + koff, bufc + 16384 + c * 4096 + tid * 16);
    }
}

__device__ __forceinline__ void compute_bk64(const short* buf, const int* aoff, const int* boff,
                                             floatx4 acc[4][4]) {
    const short* sA = buf;
    const short* sB = buf + 8192;
    short8 a0[4], a1[4], b0[4], b1[4];
#pragma unroll
    for (int i = 0; i < 4; ++i) {
        a0[i] = *(const short8*)(sA + aoff[i]);
        a1[i] = *(const short8*)(sA + (aoff[i] ^ 32));
        b0[i] = *(const short8*)(sB + boff[i]);
        b1[i] = *(const short8*)(sB + (boff[i] ^ 32));
    }
    asm volatile("s_waitcnt lgkmcnt(0)" ::: "memory");
    __builtin_amdgcn_sched_barrier(0);
    __builtin_amdgcn_s_setprio(1);
#pragma unroll
    for (int i = 0; i < 4; ++i)
#pragma unroll
        for (int j = 0; j < 4; ++j) {
            acc[i][j] = __builtin_amdgcn_mfma_f32_16x16x32_bf16(a0[i], b0[j], acc[i][j], 0, 0, 0);
            acc[i][j] = __builtin_amdgcn_mfma_f32_16x16x32_bf16(a1[i], b1[j], acc[i][j], 0, 0, 0);
        }
    __builtin_amdgcn_s_setprio(0);
}

__device__ __forceinline__ void core64db(const unsigned short* const* pa,
                                         const unsigned short* const* pb,
                                         short* smem, int nkt, int wm, int wn,
                                         int tid, int lane, floatx4 acc[4][4]) {
    char* b0c = (char*)smem;
    char* b1c = b0c + 32768;
    const int sl = ((lane >> 4) ^ (lane & 7)) * 8;
    int aoff[4], boff[4];
#pragma unroll
    for (int i = 0; i < 4; ++i) {
        aoff[i] = (wm * 64 + i * 16 + (lane & 15)) * 64 + sl;
        boff[i] = (wn * 64 + i * 16 + (lane & 15)) * 64 + sl;
    }
    stage_bk64(pa, pb, b0c, 0, tid);
    __syncthreads();
#pragma unroll 1
    for (int kt = 0; kt < nkt; kt += 2) {
        if (kt + 1 < nkt) stage_bk64(pa, pb, b1c, (kt + 1) * 64, tid);
        compute_bk64(smem, aoff, boff, acc);
        __syncthreads();
        if (kt + 2 < nkt) stage_bk64(pa, pb, b0c, (kt + 2) * 64, tid);
        compute_bk64(smem + 16384, aoff, boff, acc);
        __syncthreads();
    }
}

// GEMM3: out = ymix @ Wc^T + bc
__global__ __launch_bounds__(256) void k_gemm_out(const unsigned short* __restrict__ ymix,
                                                  const unsigned short* __restrict__ wcb,
                                                  const float* __restrict__ bc,
                                                  float* __restrict__ out) {
    const int mt = blockIdx.x >> 3, nt = blockIdx.x & 7;
    const int m0 = mt * 128, n0 = nt * 128;
    extern __shared__ short smem[];
    const int tid = threadIdx.x, lane = tid & 63, wid = tid >> 6;
    const int wm = wid >> 1, wn = wid & 1;
    const int srow = tid >> 3;
    const int cswz = ((tid & 7) ^ (srow & 7)) * 8;
    const unsigned short* pa[4];
    const unsigned short* pb[4];
#pragma unroll
    for (int c = 0; c < 4; ++c) {
        pa[c] = ymix + (size_t)(m0 + 32 * c + srow) * IN_SZ + cswz;
        int br = n0 + 32 * c + srow; if (br > NC - 1) br = NC - 1;
        pb[c] = wcb + (size_t)br * IN_SZ + cswz;
    }
    floatx4 acc[4][4] = {};
    core64db(pa, pb, smem, IN_SZ / 64, wm, wn, tid, lane, acc);
#pragma unroll
    for (int i = 0; i < 4; ++i)
#pragma unroll
        for (int j = 0; j < 4; ++j)
#pragma unroll
            for (int r = 0; r < 4; ++r) {
                int row = m0 + wm * 64 + i * 16 + (lane >> 4) * 4 + r;
                int col = n0 + wn * 64 + j * 16 + (lane & 15);
                if (col < NC)
                    out[(size_t)row * NC + col] = acc[i][j][r] + bc[col];
            }
}

extern "C" void kernel_launch(void* const* d_in, const int* in_sizes, int n_in,
                              void* d_out, int out_size, void* d_ws, size_t ws_size,
                              hipStream_t stream) {
    const float* x     = (const float*)d_in[0];
    const float* Wg    = (const float*)d_in[1];
    const float* bg    = (const float*)d_in[2];
    const float* gamma = (const float*)d_in[3];
    const float* beta  = (const float*)d_in[4];
    const float* W1    = (const float*)d_in[5];
    const float* b1    = (const float*)d_in[6];
    const float* W2    = (const float*)d_in[7];
    const float* b2    = (const float*)d_in[8];
    const float* Wc    = (const float*)d_in[9];
    const float* bc    = (const float*)d_in[10];
    float* out = (float*)d_out;

    char* ws = (char*)d_ws;
    size_t o = 0;
    auto carve = [&](size_t bytes) { char* p = ws + o; o += (bytes + 255) & ~(size_t)255; return p; };
    unsigned short* xb    = (unsigned short*)carve((size_t)B_SZ * IN_SZ * 2);
    unsigned short* w1b   = (unsigned short*)carve((size_t)HIDE * IN_SZ * 2);
    unsigned short* w2b   = (unsigned short*)carve((size_t)NE * OUTE * HIDE * 2);
    unsigned short* wcb   = (unsigned short*)carve((size_t)NC * IN_SZ * 2);
    unsigned short* h     = (unsigned short*)carve((size_t)B_SZ * HIDE * 2);
    unsigned short* parts = (unsigned short*)carve((size_t)NSPLIT * B_SZ * 2 * OUTE * 2);
    unsigned short* ymix  = (unsigned short*)carve((size_t)B_SZ * OUTE * 2);
    float* logits = (float*)carve((size_t)B_SZ * NE * 4);
    float* Gx     = (float*)carve((size_t)B_SZ * 4);
    int*   tidx   = (int*)carve((size_t)B_SZ * 2 * 4);
    float* tp     = (float*)carve((size_t)B_SZ * 2 * 4);
    int*   rowsw  = (int*)carve((size_t)B_SZ * 2 * 4);
    int*   slotof = (int*)carve((size_t)B_SZ * 2 * 4);
    int*   ctrl   = (int*)carve(256);
    int* counts  = ctrl;
    int* cursors = ctrl + 8;
    int* offs    = ctrl + 16;
    float* gsum  = (float*)(ctrl + 24);

    // dynamic LDS caps (idempotent, not captured)
    hipFuncSetAttribute((const void*)k_h8,       hipFuncAttributeMaxDynamicSharedMemorySize, 131072);
    hipFuncSetAttribute((const void*)k_moe,      hipFuncAttributeMaxDynamicSharedMemorySize, 131072);
    hipFuncSetAttribute((const void*)k_gemm_out, hipFuncAttributeMaxDynamicSharedMemorySize, 65536);

    k_cvt<<<2048, 256, 0, stream>>>(x,  xb,  B_SZ * IN_SZ);
    k_cvt<<<2048, 256, 0, stream>>>(W1, w1b, HIDE * IN_SZ);
    k_cvt<<<2048, 256, 0, stream>>>(W2, w2b, NE * OUTE * HIDE);
    k_cvt<<<2048, 256, 0, stream>>>(Wc, wcb, NC * IN_SZ);

    k_gate<<<B_SZ / 4, 256, 0, stream>>>(x, Wg, bg, logits, Gx);
    k_gsum<<<1, 1024, 0, stream>>>(Gx, gsum);
    k_zeroctrl<<<1, 64, 0, stream>>>(ctrl);
    k_topk<<<B_SZ / 256, 256, 0, stream>>>(logits, Gx, gsum, gamma, beta, tidx, tp, counts);
    k_offsets<<<1, 64, 0, stream>>>(counts, offs);
    k_fill<<<B_SZ / 256, 256, 0, stream>>>(tidx, tp, offs, cursors, rowsw, slotof);

    k_h8<<<(B_SZ / 256) * (HIDE / 256), 512, 131072, stream>>>(xb, w1b, b1, h);
    k_moe<<<NE * NSPLIT * 4 * MTT, 512, 131072, stream>>>(h, w2b, counts, offs, rowsw, parts);
    k_reduce<<<B_SZ, 256, 0, stream>>>(parts, slotof, tidx, tp, b2, ymix);
    k_gemm_out<<<(B_SZ / 128) * 8, 256, 65536, stream>>>(ymix, wcb, bc, out);
}

// Round 9
// 1225.961 us; speedup vs baseline: 1.1377x; 1.1377x over previous
//
#include <hip/hip_runtime.h>
#include <stdint.h>

#define B_SZ   4096
#define IN_SZ  1024
#define NE     8
#define NC     1000
#define HIDE   16384   // HID*E
#define OUTE   1024    // OUT per expert
#define GEPS   1e-6f
#define NSPLIT 2
#define KSPL   8192    // HIDE / NSPLIT

typedef __attribute__((ext_vector_type(8))) short short8;
typedef __attribute__((ext_vector_type(4))) float floatx4;

__device__ __forceinline__ unsigned short f2bf(float f) {
    unsigned u = __float_as_uint(f);
    u += 0x7fffu + ((u >> 16) & 1u);
    return (unsigned short)(u >> 16);
}
__device__ __forceinline__ float bf2f(unsigned short h) {
    return __uint_as_float(((unsigned)h) << 16);
}

__device__ __forceinline__ void async16(const void* g, void* l) {
    __builtin_amdgcn_global_load_lds(
        (const __attribute__((address_space(1))) void*)g,
        (__attribute__((address_space(3))) void*)l, 16, 0, 0);
}

// ---------------- conversion fp32 -> bf16 ---------------------------------------
__global__ __launch_bounds__(256) void k_cvt(const float* __restrict__ src,
                                             unsigned short* __restrict__ dst, int n) {
    int i = (blockIdx.x * 256 + threadIdx.x) * 4;
    int stride = gridDim.x * 256 * 4;
    for (; i < n; i += stride) {
        float4 v = *(const float4*)(src + i);
        ushort4 o;
        o.x = f2bf(v.x); o.y = f2bf(v.y); o.z = f2bf(v.z); o.w = f2bf(v.w);
        *(ushort4*)(dst + i) = o;
    }
}

// ---------------- gating (fp32 exact) -------------------------------------------
__global__ __launch_bounds__(256) void k_gate(const float* __restrict__ x,
                                              const float* __restrict__ Wg,
                                              const float* __restrict__ bg,
                                              float* __restrict__ logits,
                                              float* __restrict__ Gx) {
    int wid = threadIdx.x >> 6, lane = threadIdx.x & 63;
    int b = blockIdx.x * 4 + wid;
    const float* xr = x + (size_t)b * IN_SZ;
    float xv[16];
#pragma unroll
    for (int t = 0; t < 16; ++t) xv[t] = xr[lane + 64 * t];
    float lg[NE];
#pragma unroll
    for (int e = 0; e < NE; ++e) {
        const float* wr = Wg + e * IN_SZ;
        float s = 0.f;
#pragma unroll
        for (int t = 0; t < 16; ++t) s += xv[t] * wr[lane + 64 * t];
#pragma unroll
        for (int m = 32; m >= 1; m >>= 1) s += __shfl_xor(s, m, 64);
        lg[e] = s + bg[e];
    }
    if (lane == 0) {
        float ss = 0.f;
#pragma unroll
        for (int e = 0; e < NE; ++e) { logits[b * NE + e] = lg[e]; ss += lg[e] * lg[e]; }
        Gx[b] = sqrtf(ss);
    }
}

__global__ __launch_bounds__(1024) void k_gsum(const float* __restrict__ Gx, float* __restrict__ gsum) {
    __shared__ float sm[1024];
    int t = threadIdx.x;
    sm[t] = Gx[t] + Gx[t + 1024] + Gx[t + 2048] + Gx[t + 3072];
    __syncthreads();
    for (int m = 512; m >= 1; m >>= 1) {
        if (t < m) sm[t] += sm[t + m];
        __syncthreads();
    }
    if (t == 0) gsum[0] = sm[0];
}

__global__ void k_zeroctrl(int* ctrl) {
    if (threadIdx.x < 24) ctrl[threadIdx.x] = 0;
}

__global__ __launch_bounds__(256) void k_topk(const float* __restrict__ logits,
                                              const float* __restrict__ Gx,
                                              const float* __restrict__ gsum,
                                              const float* __restrict__ gamma,
                                              const float* __restrict__ beta,
                                              int* __restrict__ tidx, float* __restrict__ tp,
                                              int* __restrict__ counts) {
    int b = blockIdx.x * 256 + threadIdx.x;
    float nx = Gx[b] / (gsum[0] * (1.0f / (float)B_SZ) + GEPS);
    float l[NE];
    float mx = -1e30f;
#pragma unroll
    for (int e = 0; e < NE; ++e) {
        l[e] = gamma[e] * (logits[b * NE + e] * nx) + beta[e];
        mx = fmaxf(mx, l[e]);
    }
    float se = 0.f;
#pragma unroll
    for (int e = 0; e < NE; ++e) { l[e] = expf(l[e] - mx); se += l[e]; }
    float inv = 1.f / se;
    int i0 = 0; float p0 = l[0];
#pragma unroll
    for (int e = 1; e < NE; ++e) if (l[e] > p0) { p0 = l[e]; i0 = e; }
    int i1 = -1; float p1 = -1.f;
#pragma unroll
    for (int e = 0; e < NE; ++e) if (e != i0 && l[e] > p1) { p1 = l[e]; i1 = e; }
    tidx[b * 2 + 0] = i0; tidx[b * 2 + 1] = i1;
    tp[b * 2 + 0] = p0 * inv; tp[b * 2 + 1] = p1 * inv;
    atomicAdd(&counts[i0], 1);
    atomicAdd(&counts[i1], 1);
}

__global__ void k_offsets(const int* __restrict__ counts, int* __restrict__ offs) {
    if (threadIdx.x == 0) {
        int a = 0;
        for (int e = 0; e < NE; ++e) { offs[e] = a; a += counts[e]; }
    }
}

__global__ __launch_bounds__(256) void k_fill(const int* __restrict__ tidx, const float* __restrict__ tp,
                                              const int* __restrict__ offs, int* __restrict__ cursors,
                                              int* __restrict__ rowsw, int* __restrict__ slotof) {
    int b = blockIdx.x * 256 + threadIdx.x;
#pragma unroll
    for (int k = 0; k < 2; ++k) {
        int e = tidx[b * 2 + k];
        int pos = atomicAdd(&cursors[e], 1);
        int at = offs[e] + pos;
        rowsw[at] = b * 2 + k;
        slotof[b * 2 + k] = at;
    }
}

// ====== 128x128 / BK=64, XOR-swizzled, double-buffered (round-6 proven) =========
// LDS buffer = [A 16KB | B 16KB]; buf0 @0, buf1 @32KB. LDS[r][slot] holds global
// chunk slot^(r&7); ds_read offsets swizzled identically (0 conflicts, r5-r7).

__device__ __forceinline__ void compute_bk64(const short* buf, const int* aoff, const int* boff,
                                             floatx4 acc[4][4]) {
    const short* sA = buf;
    const short* sB = buf + 8192;
    short8 a0[4], a1[4], b0[4], b1[4];
#pragma unroll
    for (int i = 0; i < 4; ++i) {
        a0[i] = *(const short8*)(sA + aoff[i]);
        a1[i] = *(const short8*)(sA + (aoff[i] ^ 32));
        b0[i] = *(const short8*)(sB + boff[i]);
        b1[i] = *(const short8*)(sB + (boff[i] ^ 32));
    }
    asm volatile("s_waitcnt lgkmcnt(0)" ::: "memory");
    __builtin_amdgcn_sched_barrier(0);
    __builtin_amdgcn_s_setprio(1);
#pragma unroll
    for (int i = 0; i < 4; ++i)
#pragma unroll
        for (int j = 0; j < 4; ++j) {
            acc[i][j] = __builtin_amdgcn_mfma_f32_16x16x32_bf16(a0[i], b0[j], acc[i][j], 0, 0, 0);
            acc[i][j] = __builtin_amdgcn_mfma_f32_16x16x32_bf16(a1[i], b1[j], acc[i][j], 0, 0, 0);
        }
    __builtin_amdgcn_s_setprio(0);
}

// full-tile stage (A+B both bf16 via global_load_lds) — for k_h8 / k_gemm_out
__device__ __forceinline__ void stage_bk64(const unsigned short* const* pa,
                                           const unsigned short* const* pb,
                                           char* bufc, int koff, int tid) {
#pragma unroll
    for (int c = 0; c < 4; ++c) {
        async16(pa[c] + koff, bufc + c * 4096 + tid * 16);
        async16(pb[c] + koff, bufc + 16384 + c * 4096 + tid * 16);
    }
}

__device__ __forceinline__ void core64db(const unsigned short* const* pa,
                                         const unsigned short* const* pb,
                                         short* smem, int nkt, int wm, int wn,
                                         int tid, int lane, floatx4 acc[4][4]) {
    char* b0c = (char*)smem;
    char* b1c = b0c + 32768;
    const int sl = ((lane >> 4) ^ (lane & 7)) * 8;
    int aoff[4], boff[4];
#pragma unroll
    for (int i = 0; i < 4; ++i) {
        aoff[i] = (wm * 64 + i * 16 + (lane & 15)) * 64 + sl;
        boff[i] = (wn * 64 + i * 16 + (lane & 15)) * 64 + sl;
    }
    stage_bk64(pa, pb, b0c, 0, tid);
    __syncthreads();
#pragma unroll 1
    for (int kt = 0; kt < nkt; kt += 2) {
        if (kt + 1 < nkt) stage_bk64(pa, pb, b1c, (kt + 1) * 64, tid);
        compute_bk64(smem, aoff, boff, acc);
        __syncthreads();
        if (kt + 2 < nkt) stage_bk64(pa, pb, b0c, (kt + 2) * 64, tid);
        compute_bk64(smem + 16384, aoff, boff, acc);
        __syncthreads();
    }
}

// ---- moe-specific staging: A bf16 via global_load_lds; B fp32 reg-staged ------
__device__ __forceinline__ void stageA4(const unsigned short* const* pa,
                                        char* bufc, int koff, int tid) {
#pragma unroll
    for (int c = 0; c < 4; ++c)
        async16(pa[c] + koff, bufc + c * 4096 + tid * 16);
}

__device__ __forceinline__ void loadB8(float4* u, const float* const* pbf, int koff) {
#pragma unroll
    for (int c = 0; c < 4; ++c) {
        const float4* p = (const float4*)(pbf[c] + koff);
        u[2 * c]     = p[0];
        u[2 * c + 1] = p[1];
    }
}

// cvt_pk (HW RNE, bit-identical to f2bf for normals) + linear ds_write_b128.
// Linear dest + inverse-swizzled per-lane SOURCE == the pre-swizzled pattern.
__device__ __forceinline__ void cvtwriteB(const float4* u, char* bufc, int tid) {
#pragma unroll
    for (int c = 0; c < 4; ++c) {
        uint4 w;
        asm volatile("v_cvt_pk_bf16_f32 %0, %1, %2" : "=v"(w.x) : "v"(u[2*c].x),   "v"(u[2*c].y));
        asm volatile("v_cvt_pk_bf16_f32 %0, %1, %2" : "=v"(w.y) : "v"(u[2*c].z),   "v"(u[2*c].w));
        asm volatile("v_cvt_pk_bf16_f32 %0, %1, %2" : "=v"(w.z) : "v"(u[2*c+1].x), "v"(u[2*c+1].y));
        asm volatile("v_cvt_pk_bf16_f32 %0, %1, %2" : "=v"(w.w) : "v"(u[2*c+1].z), "v"(u[2*c+1].w));
        *(uint4*)(bufc + 16384 + c * 4096 + tid * 16) = w;
    }
}

// GEMM1: h = relu(x @ W1^T + b1)  [4096,1024] x [16384,1024]^T -> bf16 [4096,16384]
__global__ __launch_bounds__(256) void k_h8(const unsigned short* __restrict__ xb,
                                            const unsigned short* __restrict__ w1b,
                                            const float* __restrict__ b1,
                                            unsigned short* __restrict__ hout) {
    extern __shared__ short smem[];
    const int tid = threadIdx.x, lane = tid & 63, wid = tid >> 6;
    const int wm = wid >> 1, wn = wid & 1;
    const int wg = (blockIdx.x & 7) * (gridDim.x >> 3) + (blockIdx.x >> 3);
    const int mt = wg & 31, nt = wg >> 5;
    const int m0 = mt * 128, n0 = nt * 128;
    const int srow = tid >> 3;
    const int cswz = ((tid & 7) ^ (srow & 7)) * 8;
    const unsigned short* pa[4];
    const unsigned short* pb[4];
#pragma unroll
    for (int c = 0; c < 4; ++c) {
        pa[c] = xb  + (size_t)(m0 + 32 * c + srow) * IN_SZ + cswz;
        pb[c] = w1b + (size_t)(n0 + 32 * c + srow) * IN_SZ + cswz;
    }
    floatx4 acc[4][4] = {};
    core64db(pa, pb, smem, IN_SZ / 64, wm, wn, tid, lane, acc);
#pragma unroll
    for (int i = 0; i < 4; ++i)
#pragma unroll
        for (int j = 0; j < 4; ++j)
#pragma unroll
            for (int r = 0; r < 4; ++r) {
                int row = m0 + wm * 64 + i * 16 + (lane >> 4) * 4 + r;
                int col = n0 + wn * 64 + j * 16 + (lane & 15);
                float v = acc[i][j][r] + b1[col];
                hout[(size_t)row * HIDE + col] = f2bf(fmaxf(v, 0.f));
            }
}

// GEMM2 grouped, split-K=2: gathered h rows (bf16, gload_lds) x W2 (fp32 inline-cvt)
__global__ __launch_bounds__(256) void k_moe(const unsigned short* __restrict__ h,
                                             const float* __restrict__ W2,
                                             const int* __restrict__ counts,
                                             const int* __restrict__ offs,
                                             const int* __restrict__ rowsw,
                                             unsigned short* __restrict__ parts) {
    // grid 4096 = 8e x 2sp x 8nt x 32mt; mt innermost -> same-XCD share B-panel
    const int wg = (blockIdx.x & 7) * (gridDim.x >> 3) + (blockIdx.x >> 3);
    const int mt = wg & 31, nt = (wg >> 5) & 7, sp = (wg >> 8) & 1, e = wg >> 9;
    const int gn = counts[e];
    if (mt * 128 >= gn) return;
    const int gbase = offs[e];
    extern __shared__ short smem[];
    char* b0c = (char*)smem;
    char* b1c = b0c + 32768;
    const int tid = threadIdx.x, lane = tid & 63, wid = tid >> 6;
    const int wm = wid >> 1, wn = wid & 1;
    const int srow = tid >> 3;
    const int csl = (tid & 7) ^ (srow & 7);     // inverse-swizzled source chunk
    const unsigned short* pa[4];
    const float* pbf[4];
#pragma unroll
    for (int c = 0; c < 4; ++c) {
        int lr = mt * 128 + 32 * c + srow;
        if (lr > gn - 1) lr = gn - 1;
        int grow = rowsw[gbase + lr] >> 1;
        pa[c] = h + (size_t)grow * HIDE + sp * KSPL + csl * 8;
        int brow = e * OUTE + nt * 128 + 32 * c + srow;
        pbf[c] = W2 + (size_t)brow * HIDE + sp * KSPL + csl * 8;
    }
    const int sl = ((lane >> 4) ^ (lane & 7)) * 8;
    int aoff[4], boff[4];
#pragma unroll
    for (int i = 0; i < 4; ++i) {
        aoff[i] = (wm * 64 + i * 16 + (lane & 15)) * 64 + sl;
        boff[i] = (wn * 64 + i * 16 + (lane & 15)) * 64 + sl;
    }
    floatx4 acc[4][4] = {};
    const int nkt = KSPL / 64;
    // prologue: tile 0 (A async + B reg-cvt, serial once)
    stageA4(pa, b0c, 0, tid);
    {
        float4 u[8];
        loadB8(u, pbf, 0);
        cvtwriteB(u, b0c, tid);
    }
    __syncthreads();
#pragma unroll 1
    for (int kt = 0; kt < nkt; kt += 2) {
        {
            float4 u[8];
            if (kt + 1 < nkt) { loadB8(u, pbf, (kt + 1) * 64); stageA4(pa, b1c, (kt + 1) * 64, tid); }
            compute_bk64(smem, aoff, boff, acc);
            if (kt + 1 < nkt) cvtwriteB(u, b1c, tid);   // write-late: load latency hidden under MFMA
        }
        __syncthreads();
        {
            float4 u[8];
            if (kt + 2 < nkt) { loadB8(u, pbf, (kt + 2) * 64); stageA4(pa, b0c, (kt + 2) * 64, tid); }
            compute_bk64(smem + 16384, aoff, boff, acc);
            if (kt + 2 < nkt) cvtwriteB(u, b0c, tid);
        }
        __syncthreads();
    }
    unsigned short* pbase = parts + (size_t)sp * B_SZ * 2 * OUTE;
#pragma unroll
    for (int i = 0; i < 4; ++i)
#pragma unroll
        for (int j = 0; j < 4; ++j)
#pragma unroll
            for (int r = 0; r < 4; ++r) {
                int lr = mt * 128 + wm * 64 + i * 16 + (lane >> 4) * 4 + r;
                if (lr < gn) {
                    int at = gbase + lr;
                    int col = nt * 128 + wn * 64 + j * 16 + (lane & 15);
                    pbase[(size_t)at * OUTE + col] = f2bf(acc[i][j][r]);
                }
            }
}

// reduce: ymix[b] = sum_k tp[b,k] * (sum_sp parts[sp][slot(b,k)] + b2[e_k])
__global__ __launch_bounds__(256) void k_reduce(const unsigned short* __restrict__ parts,
                                                const int* __restrict__ slotof,
                                                const int* __restrict__ tidx,
                                                const float* __restrict__ tp,
                                                const float* __restrict__ b2,
                                                unsigned short* __restrict__ ymix) {
    int i = blockIdx.x * 256 + threadIdx.x;   // B_SZ * 256 threads, 4 cols each
    int b = i >> 8, col = (i & 255) * 4;
    int at0 = slotof[b * 2], at1 = slotof[b * 2 + 1];
    int e0 = tidx[b * 2], e1 = tidx[b * 2 + 1];
    float q0 = tp[b * 2], q1 = tp[b * 2 + 1];
    float y0[4] = {0.f, 0.f, 0.f, 0.f}, y1[4] = {0.f, 0.f, 0.f, 0.f};
#pragma unroll
    for (int sp = 0; sp < NSPLIT; ++sp) {
        ushort4 u0 = *(const ushort4*)(parts + ((size_t)sp * B_SZ * 2 + at0) * OUTE + col);
        ushort4 u1 = *(const ushort4*)(parts + ((size_t)sp * B_SZ * 2 + at1) * OUTE + col);
        y0[0] += bf2f(u0.x); y0[1] += bf2f(u0.y); y0[2] += bf2f(u0.z); y0[3] += bf2f(u0.w);
        y1[0] += bf2f(u1.x); y1[1] += bf2f(u1.y); y1[2] += bf2f(u1.z); y1[3] += bf2f(u1.w);
    }
    float4 bb0 = *(const float4*)(b2 + (size_t)e0 * OUTE + col);
    float4 bb1 = *(const float4*)(b2 + (size_t)e1 * OUTE + col);
    ushort4 o;
    o.x = f2bf(q0 * (y0[0] + bb0.x) + q1 * (y1[0] + bb1.x));
    o.y = f2bf(q0 * (y0[1] + bb0.y) + q1 * (y1[1] + bb1.y));
    o.z = f2bf(q0 * (y0[2] + bb0.z) + q1 * (y1[2] + bb1.z));
    o.w = f2bf(q0 * (y0[3] + bb0.w) + q1 * (y1[3] + bb1.w));
    *(ushort4*)(ymix + (size_t)b * OUTE + col) = o;
}

// GEMM3: out = ymix @ Wc^T + bc  (r6 core, B rows clamped to NC)
__global__ __launch_bounds__(256) void k_gemm_out(const unsigned short* __restrict__ ymix,
                                                  const unsigned short* __restrict__ wcb,
                                                  const float* __restrict__ bc,
                                                  float* __restrict__ out) {
    const int mt = blockIdx.x >> 3, nt = blockIdx.x & 7;
    const int m0 = mt * 128, n0 = nt * 128;
    extern __shared__ short smem[];
    const int tid = threadIdx.x, lane = tid & 63, wid = tid >> 6;
    const int wm = wid >> 1, wn = wid & 1;
    const int srow = tid >> 3;
    const int cswz = ((tid & 7) ^ (srow & 7)) * 8;
    const unsigned short* pa[4];
    const unsigned short* pb[4];
#pragma unroll
    for (int c = 0; c < 4; ++c) {
        pa[c] = ymix + (size_t)(m0 + 32 * c + srow) * IN_SZ + cswz;
        int br = n0 + 32 * c + srow; if (br > NC - 1) br = NC - 1;
        pb[c] = wcb + (size_t)br * IN_SZ + cswz;
    }
    floatx4 acc[4][4] = {};
    core64db(pa, pb, smem, IN_SZ / 64, wm, wn, tid, lane, acc);
#pragma unroll
    for (int i = 0; i < 4; ++i)
#pragma unroll
        for (int j = 0; j < 4; ++j)
#pragma unroll
            for (int r = 0; r < 4; ++r) {
                int row = m0 + wm * 64 + i * 16 + (lane >> 4) * 4 + r;
                int col = n0 + wn * 64 + j * 16 + (lane & 15);
                if (col < NC)
                    out[(size_t)row * NC + col] = acc[i][j][r] + bc[col];
            }
}

extern "C" void kernel_launch(void* const* d_in, const int* in_sizes, int n_in,
                              void* d_out, int out_size, void* d_ws, size_t ws_size,
                              hipStream_t stream) {
    const float* x     = (const float*)d_in[0];
    const float* Wg    = (const float*)d_in[1];
    const float* bg    = (const float*)d_in[2];
    const float* gamma = (const float*)d_in[3];
    const float* beta  = (const float*)d_in[4];
    const float* W1    = (const float*)d_in[5];
    const float* b1    = (const float*)d_in[6];
    const float* W2    = (const float*)d_in[7];
    const float* b2    = (const float*)d_in[8];
    const float* Wc    = (const float*)d_in[9];
    const float* bc    = (const float*)d_in[10];
    float* out = (float*)d_out;

    char* ws = (char*)d_ws;
    size_t o = 0;
    auto carve = [&](size_t bytes) { char* p = ws + o; o += (bytes + 255) & ~(size_t)255; return p; };
    unsigned short* xb    = (unsigned short*)carve((size_t)B_SZ * IN_SZ * 2);
    unsigned short* w1b   = (unsigned short*)carve((size_t)HIDE * IN_SZ * 2);
    unsigned short* wcb   = (unsigned short*)carve((size_t)NC * IN_SZ * 2);
    unsigned short* h     = (unsigned short*)carve((size_t)B_SZ * HIDE * 2);
    unsigned short* parts = (unsigned short*)carve((size_t)NSPLIT * B_SZ * 2 * OUTE * 2);
    unsigned short* ymix  = (unsigned short*)carve((size_t)B_SZ * OUTE * 2);
    float* logits = (float*)carve((size_t)B_SZ * NE * 4);
    float* Gx     = (float*)carve((size_t)B_SZ * 4);
    int*   tidx   = (int*)carve((size_t)B_SZ * 2 * 4);
    float* tp     = (float*)carve((size_t)B_SZ * 2 * 4);
    int*   rowsw  = (int*)carve((size_t)B_SZ * 2 * 4);
    int*   slotof = (int*)carve((size_t)B_SZ * 2 * 4);
    int*   ctrl   = (int*)carve(256);
    int* counts  = ctrl;
    int* cursors = ctrl + 8;
    int* offs    = ctrl + 16;
    float* gsum  = (float*)(ctrl + 24);

    // 64KB dynamic LDS for the dbuf GEMM kernels (idempotent, not captured)
    hipFuncSetAttribute((const void*)k_h8,       hipFuncAttributeMaxDynamicSharedMemorySize, 65536);
    hipFuncSetAttribute((const void*)k_moe,      hipFuncAttributeMaxDynamicSharedMemorySize, 65536);
    hipFuncSetAttribute((const void*)k_gemm_out, hipFuncAttributeMaxDynamicSharedMemorySize, 65536);

    k_cvt<<<2048, 256, 0, stream>>>(x,  xb,  B_SZ * IN_SZ);
    k_cvt<<<2048, 256, 0, stream>>>(W1, w1b, HIDE * IN_SZ);
    k_cvt<<<512,  256, 0, stream>>>(Wc, wcb, NC * IN_SZ);

    k_gate<<<B_SZ / 4, 256, 0, stream>>>(x, Wg, bg, logits, Gx);
    k_gsum<<<1, 1024, 0, stream>>>(Gx, gsum);
    k_zeroctrl<<<1, 64, 0, stream>>>(ctrl);
    k_topk<<<B_SZ / 256, 256, 0, stream>>>(logits, Gx, gsum, gamma, beta, tidx, tp, counts);
    k_offsets<<<1, 64, 0, stream>>>(counts, offs);
    k_fill<<<B_SZ / 256, 256, 0, stream>>>(tidx, tp, offs, cursors, rowsw, slotof);

    k_h8<<<(B_SZ / 128) * (HIDE / 128), 256, 65536, stream>>>(xb, w1b, b1, h);
    k_moe<<<NE * 32 * 8 * NSPLIT, 256, 65536, stream>>>(h, W2, counts, offs, rowsw, parts);
    k_reduce<<<B_SZ, 256, 0, stream>>>(parts, slotof, tidx, tp, b2, ymix);
    k_gemm_out<<<(B_SZ / 128) * 8, 256, 65536, stream>>>(ymix, wcb, bc, out);
}

// Round 10
// 922.290 us; speedup vs baseline: 1.5122x; 1.3293x over previous
//
#include <hip/hip_runtime.h>
#include <stdint.h>

#define B_SZ   4096
#define IN_SZ  1024
#define NE     8
#define NC     1000
#define HIDE   16384   // HID*E
#define OUTE   1024    // OUT per expert
#define GEPS   1e-6f
#define NSPLIT 2
#define KSPL   8192    // HIDE / NSPLIT

typedef __attribute__((ext_vector_type(8))) short short8;
typedef __attribute__((ext_vector_type(4))) float floatx4;

__device__ __forceinline__ unsigned short f2bf(float f) {
    unsigned u = __float_as_uint(f);
    u += 0x7fffu + ((u >> 16) & 1u);
    return (unsigned short)(u >> 16);
}
__device__ __forceinline__ float bf2f(unsigned short h) {
    return __uint_as_float(((unsigned)h) << 16);
}

__device__ __forceinline__ void async16(const void* g, void* l) {
    __builtin_amdgcn_global_load_lds(
        (const __attribute__((address_space(1))) void*)g,
        (__attribute__((address_space(3))) void*)l, 16, 0, 0);
}

// ---------------- conversion fp32 -> bf16 (8-wide: 2x16B load, 1x16B store) -----
__global__ __launch_bounds__(256) void k_cvt(const float* __restrict__ src,
                                             unsigned short* __restrict__ dst, int n) {
    int i = (blockIdx.x * 256 + threadIdx.x) * 8;
    int stride = gridDim.x * 256 * 8;
    for (; i < n; i += stride) {
        float4 v0 = *(const float4*)(src + i);
        float4 v1 = *(const float4*)(src + i + 4);
        ushort4 o0, o1;
        o0.x = f2bf(v0.x); o0.y = f2bf(v0.y); o0.z = f2bf(v0.z); o0.w = f2bf(v0.w);
        o1.x = f2bf(v1.x); o1.y = f2bf(v1.y); o1.z = f2bf(v1.z); o1.w = f2bf(v1.w);
        uint4 w;
        w.x = (unsigned)o0.x | ((unsigned)o0.y << 16);
        w.y = (unsigned)o0.z | ((unsigned)o0.w << 16);
        w.z = (unsigned)o1.x | ((unsigned)o1.y << 16);
        w.w = (unsigned)o1.z | ((unsigned)o1.w << 16);
        *(uint4*)(dst + i) = w;
    }
}

// ---------------- gating (fp32 exact) + emits bf16 copy of x --------------------
__global__ __launch_bounds__(256) void k_gate(const float* __restrict__ x,
                                              const float* __restrict__ Wg,
                                              const float* __restrict__ bg,
                                              float* __restrict__ logits,
                                              float* __restrict__ Gx,
                                              unsigned short* __restrict__ xb) {
    int wid = threadIdx.x >> 6, lane = threadIdx.x & 63;
    int b = blockIdx.x * 4 + wid;
    const float* xr = x + (size_t)b * IN_SZ;
    float xv[16];
#pragma unroll
    for (int t = 0; t < 16; ++t) xv[t] = xr[lane + 64 * t];
    // bf16 side-product (coalesced 128B per t across the wave)
    unsigned short* xbr = xb + (size_t)b * IN_SZ;
#pragma unroll
    for (int t = 0; t < 16; ++t) xbr[lane + 64 * t] = f2bf(xv[t]);
    float lg[NE];
#pragma unroll
    for (int e = 0; e < NE; ++e) {
        const float* wr = Wg + e * IN_SZ;
        float s = 0.f;
#pragma unroll
        for (int t = 0; t < 16; ++t) s += xv[t] * wr[lane + 64 * t];
#pragma unroll
        for (int m = 32; m >= 1; m >>= 1) s += __shfl_xor(s, m, 64);
        lg[e] = s + bg[e];
    }
    if (lane == 0) {
        float ss = 0.f;
#pragma unroll
        for (int e = 0; e < NE; ++e) { logits[b * NE + e] = lg[e]; ss += lg[e] * lg[e]; }
        Gx[b] = sqrtf(ss);
    }
}

// batch-sum of Gx; also zeroes the routing control block (saves a launch)
__global__ __launch_bounds__(1024) void k_gsum(const float* __restrict__ Gx,
                                               float* __restrict__ gsum, int* __restrict__ ctrl) {
    __shared__ float sm[1024];
    int t = threadIdx.x;
    if (t < 24) ctrl[t] = 0;
    sm[t] = Gx[t] + Gx[t + 1024] + Gx[t + 2048] + Gx[t + 3072];
    __syncthreads();
    for (int m = 512; m >= 1; m >>= 1) {
        if (t < m) sm[t] += sm[t + m];
        __syncthreads();
    }
    if (t == 0) gsum[0] = sm[0];
}

__global__ __launch_bounds__(256) void k_topk(const float* __restrict__ logits,
                                              const float* __restrict__ Gx,
                                              const float* __restrict__ gsum,
                                              const float* __restrict__ gamma,
                                              const float* __restrict__ beta,
                                              int* __restrict__ tidx, float* __restrict__ tp,
                                              int* __restrict__ counts) {
    int b = blockIdx.x * 256 + threadIdx.x;
    float nx = Gx[b] / (gsum[0] * (1.0f / (float)B_SZ) + GEPS);
    float l[NE];
    float mx = -1e30f;
#pragma unroll
    for (int e = 0; e < NE; ++e) {
        l[e] = gamma[e] * (logits[b * NE + e] * nx) + beta[e];
        mx = fmaxf(mx, l[e]);
    }
    float se = 0.f;
#pragma unroll
    for (int e = 0; e < NE; ++e) { l[e] = expf(l[e] - mx); se += l[e]; }
    float inv = 1.f / se;
    int i0 = 0; float p0 = l[0];
#pragma unroll
    for (int e = 1; e < NE; ++e) if (l[e] > p0) { p0 = l[e]; i0 = e; }
    int i1 = -1; float p1 = -1.f;
#pragma unroll
    for (int e = 0; e < NE; ++e) if (e != i0 && l[e] > p1) { p1 = l[e]; i1 = e; }
    tidx[b * 2 + 0] = i0; tidx[b * 2 + 1] = i1;
    tp[b * 2 + 0] = p0 * inv; tp[b * 2 + 1] = p1 * inv;
    atomicAdd(&counts[i0], 1);
    atomicAdd(&counts[i1], 1);
}

__global__ void k_offsets(const int* __restrict__ counts, int* __restrict__ offs) {
    if (threadIdx.x == 0) {
        int a = 0;
        for (int e = 0; e < NE; ++e) { offs[e] = a; a += counts[e]; }
    }
}

__global__ __launch_bounds__(256) void k_fill(const int* __restrict__ tidx, const float* __restrict__ tp,
                                              const int* __restrict__ offs, int* __restrict__ cursors,
                                              int* __restrict__ rowsw, int* __restrict__ slotof) {
    int b = blockIdx.x * 256 + threadIdx.x;
#pragma unroll
    for (int k = 0; k < 2; ++k) {
        int e = tidx[b * 2 + k];
        int pos = atomicAdd(&cursors[e], 1);
        int at = offs[e] + pos;
        rowsw[at] = b * 2 + k;
        slotof[b * 2 + k] = at;
    }
}

// ====== 128x128 / BK=64, XOR-swizzled, double-buffered (round-6 proven) =========
// LDS buffer = [A 16KB | B 16KB]; buf0 @0, buf1 @32KB. LDS[r][slot] holds global
// chunk slot^(r&7); pre-swizzled source + swizzled ds_read (0 conflicts, r5-r7).
// Per K-step: STAGE(buf^1, t+1) issued first, then ds_read buf[cur] ->
// lgkmcnt(0) -> MFMA cluster (setprio) -> __syncthreads (drain + flip).

__device__ __forceinline__ void compute_bk64(const short* buf, const int* aoff, const int* boff,
                                             floatx4 acc[4][4]) {
    const short* sA = buf;
    const short* sB = buf + 8192;
    short8 a0[4], a1[4], b0[4], b1[4];
#pragma unroll
    for (int i = 0; i < 4; ++i) {
        a0[i] = *(const short8*)(sA + aoff[i]);
        a1[i] = *(const short8*)(sA + (aoff[i] ^ 32));
        b0[i] = *(const short8*)(sB + boff[i]);
        b1[i] = *(const short8*)(sB + (boff[i] ^ 32));
    }
    asm volatile("s_waitcnt lgkmcnt(0)" ::: "memory");
    __builtin_amdgcn_sched_barrier(0);
    __builtin_amdgcn_s_setprio(1);
#pragma unroll
    for (int i = 0; i < 4; ++i)
#pragma unroll
        for (int j = 0; j < 4; ++j) {
            acc[i][j] = __builtin_amdgcn_mfma_f32_16x16x32_bf16(a0[i], b0[j], acc[i][j], 0, 0, 0);
            acc[i][j] = __builtin_amdgcn_mfma_f32_16x16x32_bf16(a1[i], b1[j], acc[i][j], 0, 0, 0);
        }
    __builtin_amdgcn_s_setprio(0);
}

__device__ __forceinline__ void stage_bk64(const unsigned short* const* pa,
                                           const unsigned short* const* pb,
                                           char* bufc, int koff, int tid) {
#pragma unroll
    for (int c = 0; c < 4; ++c) {
        async16(pa[c] + koff, bufc + c * 4096 + tid * 16);
        async16(pb[c] + koff, bufc + 16384 + c * 4096 + tid * 16);
    }
}

__device__ __forceinline__ void core64db(const unsigned short* const* pa,
                                         const unsigned short* const* pb,
                                         short* smem, int nkt, int wm, int wn,
                                         int tid, int lane, floatx4 acc[4][4]) {
    char* b0c = (char*)smem;
    char* b1c = b0c + 32768;
    const int sl = ((lane >> 4) ^ (lane & 7)) * 8;
    int aoff[4], boff[4];
#pragma unroll
    for (int i = 0; i < 4; ++i) {
        aoff[i] = (wm * 64 + i * 16 + (lane & 15)) * 64 + sl;
        boff[i] = (wn * 64 + i * 16 + (lane & 15)) * 64 + sl;
    }
    stage_bk64(pa, pb, b0c, 0, tid);
    __syncthreads();
#pragma unroll 1
    for (int kt = 0; kt < nkt; kt += 2) {
        if (kt + 1 < nkt) stage_bk64(pa, pb, b1c, (kt + 1) * 64, tid);
        compute_bk64(smem, aoff, boff, acc);
        __syncthreads();
        if (kt + 2 < nkt) stage_bk64(pa, pb, b0c, (kt + 2) * 64, tid);
        compute_bk64(smem + 16384, aoff, boff, acc);
        __syncthreads();
    }
}

// GEMM1: h = relu(x @ W1^T + b1)  [4096,1024] x [16384,1024]^T -> bf16 [4096,16384]
__global__ __launch_bounds__(256) void k_h8(const unsigned short* __restrict__ xb,
                                            const unsigned short* __restrict__ w1b,
                                            const float* __restrict__ b1,
                                            unsigned short* __restrict__ hout) {
    extern __shared__ short smem[];
    const int tid = threadIdx.x, lane = tid & 63, wid = tid >> 6;
    const int wm = wid >> 1, wn = wid & 1;
    const int wg = (blockIdx.x & 7) * (gridDim.x >> 3) + (blockIdx.x >> 3);
    const int mt = wg & 31, nt = wg >> 5;
    const int m0 = mt * 128, n0 = nt * 128;
    const int srow = tid >> 3;
    const int cswz = ((tid & 7) ^ (srow & 7)) * 8;
    const unsigned short* pa[4];
    const unsigned short* pb[4];
#pragma unroll
    for (int c = 0; c < 4; ++c) {
        pa[c] = xb  + (size_t)(m0 + 32 * c + srow) * IN_SZ + cswz;
        pb[c] = w1b + (size_t)(n0 + 32 * c + srow) * IN_SZ + cswz;
    }
    floatx4 acc[4][4] = {};
    core64db(pa, pb, smem, IN_SZ / 64, wm, wn, tid, lane, acc);
#pragma unroll
    for (int i = 0; i < 4; ++i)
#pragma unroll
        for (int j = 0; j < 4; ++j)
#pragma unroll
            for (int r = 0; r < 4; ++r) {
                int row = m0 + wm * 64 + i * 16 + (lane >> 4) * 4 + r;
                int col = n0 + wn * 64 + j * 16 + (lane & 15);
                float v = acc[i][j][r] + b1[col];
                hout[(size_t)row * HIDE + col] = f2bf(fmaxf(v, 0.f));
            }
}

// GEMM2 grouped, split-K=2: gathered h rows x W2 expert slice -> bf16 partials
__global__ __launch_bounds__(256) void k_moe(const unsigned short* __restrict__ h,
                                             const unsigned short* __restrict__ w2b,
                                             const int* __restrict__ counts,
                                             const int* __restrict__ offs,
                                             const int* __restrict__ rowsw,
                                             unsigned short* __restrict__ parts) {
    // grid 4096 = 8e x 2sp x 8nt x 32mt; mt innermost -> same-XCD share B-panel
    const int wg = (blockIdx.x & 7) * (gridDim.x >> 3) + (blockIdx.x >> 3);
    const int mt = wg & 31, nt = (wg >> 5) & 7, sp = (wg >> 8) & 1, e = wg >> 9;
    const int gn = counts[e];
    if (mt * 128 >= gn) return;
    const int gbase = offs[e];
    extern __shared__ short smem[];
    const int tid = threadIdx.x, lane = tid & 63, wid = tid >> 6;
    const int wm = wid >> 1, wn = wid & 1;
    const int srow = tid >> 3;
    const int cswz = ((tid & 7) ^ (srow & 7)) * 8;
    const unsigned short* pa[4];
    const unsigned short* pb[4];
#pragma unroll
    for (int c = 0; c < 4; ++c) {
        int lr = mt * 128 + 32 * c + srow;
        if (lr > gn - 1) lr = gn - 1;
        int grow = rowsw[gbase + lr] >> 1;
        pa[c] = h + (size_t)grow * HIDE + sp * KSPL + cswz;
        pb[c] = w2b + (size_t)(e * OUTE + nt * 128 + 32 * c + srow) * HIDE + sp * KSPL + cswz;
    }
    floatx4 acc[4][4] = {};
    core64db(pa, pb, smem, KSPL / 64, wm, wn, tid, lane, acc);
    unsigned short* pbase = parts + (size_t)sp * B_SZ * 2 * OUTE;
#pragma unroll
    for (int i = 0; i < 4; ++i)
#pragma unroll
        for (int j = 0; j < 4; ++j)
#pragma unroll
            for (int r = 0; r < 4; ++r) {
                int lr = mt * 128 + wm * 64 + i * 16 + (lane >> 4) * 4 + r;
                if (lr < gn) {
                    int at = gbase + lr;
                    int col = nt * 128 + wn * 64 + j * 16 + (lane & 15);
                    pbase[(size_t)at * OUTE + col] = f2bf(acc[i][j][r]);
                }
            }
}

// reduce: ymix[b] = sum_k tp[b,k] * (sum_sp parts[sp][slot(b,k)] + b2[e_k])
__global__ __launch_bounds__(256) void k_reduce(const unsigned short* __restrict__ parts,
                                                const int* __restrict__ slotof,
                                                const int* __restrict__ tidx,
                                                const float* __restrict__ tp,
                                                const float* __restrict__ b2,
                                                unsigned short* __restrict__ ymix) {
    int i = blockIdx.x * 256 + threadIdx.x;   // B_SZ * 256 threads, 4 cols each
    int b = i >> 8, col = (i & 255) * 4;
    int at0 = slotof[b * 2], at1 = slotof[b * 2 + 1];
    int e0 = tidx[b * 2], e1 = tidx[b * 2 + 1];
    float q0 = tp[b * 2], q1 = tp[b * 2 + 1];
    float y0[4] = {0.f, 0.f, 0.f, 0.f}, y1[4] = {0.f, 0.f, 0.f, 0.f};
#pragma unroll
    for (int sp = 0; sp < NSPLIT; ++sp) {
        ushort4 u0 = *(const ushort4*)(parts + ((size_t)sp * B_SZ * 2 + at0) * OUTE + col);
        ushort4 u1 = *(const ushort4*)(parts + ((size_t)sp * B_SZ * 2 + at1) * OUTE + col);
        y0[0] += bf2f(u0.x); y0[1] += bf2f(u0.y); y0[2] += bf2f(u0.z); y0[3] += bf2f(u0.w);
        y1[0] += bf2f(u1.x); y1[1] += bf2f(u1.y); y1[2] += bf2f(u1.z); y1[3] += bf2f(u1.w);
    }
    float4 bb0 = *(const float4*)(b2 + (size_t)e0 * OUTE + col);
    float4 bb1 = *(const float4*)(b2 + (size_t)e1 * OUTE + col);
    ushort4 o;
    o.x = f2bf(q0 * (y0[0] + bb0.x) + q1 * (y1[0] + bb1.x));
    o.y = f2bf(q0 * (y0[1] + bb0.y) + q1 * (y1[1] + bb1.y));
    o.z = f2bf(q0 * (y0[2] + bb0.z) + q1 * (y1[2] + bb1.z));
    o.w = f2bf(q0 * (y0[3] + bb0.w) + q1 * (y1[3] + bb1.w));
    *(ushort4*)(ymix + (size_t)b * OUTE + col) = o;
}

// GEMM3: out = ymix @ Wc^T + bc  (r6 core, B rows clamped to NC)
__global__ __launch_bounds__(256) void k_gemm_out(const unsigned short* __restrict__ ymix,
                                                  const unsigned short* __restrict__ wcb,
                                                  const float* __restrict__ bc,
                                                  float* __restrict__ out) {
    const int mt = blockIdx.x >> 3, nt = blockIdx.x & 7;
    const int m0 = mt * 128, n0 = nt * 128;
    extern __shared__ short smem[];
    const int tid = threadIdx.x, lane = tid & 63, wid = tid >> 6;
    const int wm = wid >> 1, wn = wid & 1;
    const int srow = tid >> 3;
    const int cswz = ((tid & 7) ^ (srow & 7)) * 8;
    const unsigned short* pa[4];
    const unsigned short* pb[4];
#pragma unroll
    for (int c = 0; c < 4; ++c) {
        pa[c] = ymix + (size_t)(m0 + 32 * c + srow) * IN_SZ + cswz;
        int br = n0 + 32 * c + srow; if (br > NC - 1) br = NC - 1;
        pb[c] = wcb + (size_t)br * IN_SZ + cswz;
    }
    floatx4 acc[4][4] = {};
    core64db(pa, pb, smem, IN_SZ / 64, wm, wn, tid, lane, acc);
#pragma unroll
    for (int i = 0; i < 4; ++i)
#pragma unroll
        for (int j = 0; j < 4; ++j)
#pragma unroll
            for (int r = 0; r < 4; ++r) {
                int row = m0 + wm * 64 + i * 16 + (lane >> 4) * 4 + r;
                int col = n0 + wn * 64 + j * 16 + (lane & 15);
                if (col < NC)
                    out[(size_t)row * NC + col] = acc[i][j][r] + bc[col];
            }
}

extern "C" void kernel_launch(void* const* d_in, const int* in_sizes, int n_in,
                              void* d_out, int out_size, void* d_ws, size_t ws_size,
                              hipStream_t stream) {
    const float* x     = (const float*)d_in[0];
    const float* Wg    = (const float*)d_in[1];
    const float* bg    = (const float*)d_in[2];
    const float* gamma = (const float*)d_in[3];
    const float* beta  = (const float*)d_in[4];
    const float* W1    = (const float*)d_in[5];
    const float* b1    = (const float*)d_in[6];
    const float* W2    = (const float*)d_in[7];
    const float* b2    = (const float*)d_in[8];
    const float* Wc    = (const float*)d_in[9];
    const float* bc    = (const float*)d_in[10];
    float* out = (float*)d_out;

    char* ws = (char*)d_ws;
    size_t o = 0;
    auto carve = [&](size_t bytes) { char* p = ws + o; o += (bytes + 255) & ~(size_t)255; return p; };
    unsigned short* xb    = (unsigned short*)carve((size_t)B_SZ * IN_SZ * 2);
    unsigned short* w1b   = (unsigned short*)carve((size_t)HIDE * IN_SZ * 2);
    unsigned short* w2b   = (unsigned short*)carve((size_t)NE * OUTE * HIDE * 2);
    unsigned short* wcb   = (unsigned short*)carve((size_t)NC * IN_SZ * 2);
    unsigned short* h     = (unsigned short*)carve((size_t)B_SZ * HIDE * 2);
    unsigned short* parts = (unsigned short*)carve((size_t)NSPLIT * B_SZ * 2 * OUTE * 2);
    unsigned short* ymix  = (unsigned short*)carve((size_t)B_SZ * OUTE * 2);
    float* logits = (float*)carve((size_t)B_SZ * NE * 4);
    float* Gx     = (float*)carve((size_t)B_SZ * 4);
    int*   tidx   = (int*)carve((size_t)B_SZ * 2 * 4);
    float* tp     = (float*)carve((size_t)B_SZ * 2 * 4);
    int*   rowsw  = (int*)carve((size_t)B_SZ * 2 * 4);
    int*   slotof = (int*)carve((size_t)B_SZ * 2 * 4);
    int*   ctrl   = (int*)carve(256);
    int* counts  = ctrl;
    int* cursors = ctrl + 8;
    int* offs    = ctrl + 16;
    float* gsum  = (float*)(ctrl + 24);

    // 64KB dynamic LDS for the dbuf GEMM kernels (idempotent, not captured)
    hipFuncSetAttribute((const void*)k_h8,       hipFuncAttributeMaxDynamicSharedMemorySize, 65536);
    hipFuncSetAttribute((const void*)k_moe,      hipFuncAttributeMaxDynamicSharedMemorySize, 65536);
    hipFuncSetAttribute((const void*)k_gemm_out, hipFuncAttributeMaxDynamicSharedMemorySize, 65536);

    k_cvt<<<2048, 256, 0, stream>>>(W1, w1b, HIDE * IN_SZ);
    k_cvt<<<2048, 256, 0, stream>>>(W2, w2b, NE * OUTE * HIDE);
    k_cvt<<<512,  256, 0, stream>>>(Wc, wcb, NC * IN_SZ);

    k_gate<<<B_SZ / 4, 256, 0, stream>>>(x, Wg, bg, logits, Gx, xb);
    k_gsum<<<1, 1024, 0, stream>>>(Gx, gsum, ctrl);
    k_topk<<<B_SZ / 256, 256, 0, stream>>>(logits, Gx, gsum, gamma, beta, tidx, tp, counts);
    k_offsets<<<1, 64, 0, stream>>>(counts, offs);
    k_fill<<<B_SZ / 256, 256, 0, stream>>>(tidx, tp, offs, cursors, rowsw, slotof);

    k_h8<<<(B_SZ / 128) * (HIDE / 128), 256, 65536, stream>>>(xb, w1b, b1, h);
    k_moe<<<NE * 32 * 8 * NSPLIT, 256, 65536, stream>>>(h, w2b, counts, offs, rowsw, parts);
    k_reduce<<<B_SZ, 256, 0, stream>>>(parts, slotof, tidx, tp, b2, ymix);
    k_gemm_out<<<(B_SZ / 128) * 8, 256, 65536, stream>>>(ymix, wcb, bc, out);
}

// Round 12
// 898.235 us; speedup vs baseline: 1.5527x; 1.0268x over previous
//
#include <hip/hip_runtime.h>
#include <stdint.h>

#define B_SZ   4096
#define IN_SZ  1024
#define NE     8
#define NC     1000
#define HIDE   16384   // HID*E
#define OUTE   1024    // OUT per expert
#define GEPS   1e-6f
#define NSPLIT 2
#define KSPL   8192    // HIDE / NSPLIT

typedef __attribute__((ext_vector_type(8))) short short8;
typedef __attribute__((ext_vector_type(4))) float floatx4;

__device__ __forceinline__ unsigned short f2bf(float f) {
    unsigned u = __float_as_uint(f);
    u += 0x7fffu + ((u >> 16) & 1u);
    return (unsigned short)(u >> 16);
}
__device__ __forceinline__ float bf2f(unsigned short h) {
    return __uint_as_float(((unsigned)h) << 16);
}

__device__ __forceinline__ void async16(const void* g, void* l) {
    __builtin_amdgcn_global_load_lds(
        (const __attribute__((address_space(1))) void*)g,
        (__attribute__((address_space(3))) void*)l, 16, 0, 0);
}

// 8-wide fp32->bf16 span conversion (grid-strided over nb blocks)
__device__ __forceinline__ void cvt_span(const float* __restrict__ src,
                                         unsigned short* __restrict__ dst,
                                         int n, int bid, int nb) {
    int i = (bid * 256 + (int)threadIdx.x) * 8;
    int stride = nb * 256 * 8;
    for (; i < n; i += stride) {
        float4 v0 = *(const float4*)(src + i);
        float4 v1 = *(const float4*)(src + i + 4);
        uint4 w;
        w.x = (unsigned)f2bf(v0.x) | ((unsigned)f2bf(v0.y) << 16);
        w.y = (unsigned)f2bf(v0.z) | ((unsigned)f2bf(v0.w) << 16);
        w.z = (unsigned)f2bf(v1.x) | ((unsigned)f2bf(v1.y) << 16);
        w.w = (unsigned)f2bf(v1.z) | ((unsigned)f2bf(v1.w) << 16);
        *(uint4*)(dst + i) = w;
    }
}

// ---------------- gating (fp32 exact) + bf16 x + W1/Wc conversion (role-split) --
// blocks [0,1024): gate rows; [1024,1536): W1 cvt (full: 512 blk x 16 iters);
// [1536,1600): Wc cvt (64 blk over 1.024M elems).
__global__ __launch_bounds__(256) void k_gatef(const float* __restrict__ x,
                                               const float* __restrict__ Wg,
                                               const float* __restrict__ bg,
                                               float* __restrict__ logits,
                                               float* __restrict__ Gx,
                                               unsigned short* __restrict__ xb,
                                               const float* __restrict__ W1,
                                               unsigned short* __restrict__ w1b,
                                               const float* __restrict__ Wc,
                                               unsigned short* __restrict__ wcb) {
    const int bid = blockIdx.x;
    if (bid >= 1024) {
        if (bid < 1536) cvt_span(W1, w1b, HIDE * IN_SZ, bid - 1024, 512);
        else            cvt_span(Wc, wcb, NC * IN_SZ,   bid - 1536, 64);
        return;
    }
    int wid = threadIdx.x >> 6, lane = threadIdx.x & 63;
    int b = bid * 4 + wid;
    const float* xr = x + (size_t)b * IN_SZ;
    float xv[16];
#pragma unroll
    for (int t = 0; t < 16; ++t) xv[t] = xr[lane + 64 * t];
    unsigned short* xbr = xb + (size_t)b * IN_SZ;
#pragma unroll
    for (int t = 0; t < 16; ++t) xbr[lane + 64 * t] = f2bf(xv[t]);
    float lg[NE];
#pragma unroll
    for (int e = 0; e < NE; ++e) {
        const float* wr = Wg + e * IN_SZ;
        float s = 0.f;
#pragma unroll
        for (int t = 0; t < 16; ++t) s += xv[t] * wr[lane + 64 * t];
#pragma unroll
        for (int m = 32; m >= 1; m >>= 1) s += __shfl_xor(s, m, 64);
        lg[e] = s + bg[e];
    }
    if (lane == 0) {
        float ss = 0.f;
#pragma unroll
        for (int e = 0; e < NE; ++e) { logits[b * NE + e] = lg[e]; ss += lg[e] * lg[e]; }
        Gx[b] = sqrtf(ss);
    }
}

// batch-sum of Gx; also zeroes the routing control block
__global__ __launch_bounds__(1024) void k_gsum(const float* __restrict__ Gx,
                                               float* __restrict__ gsum, int* __restrict__ ctrl) {
    __shared__ float sm[1024];
    int t = threadIdx.x;
    if (t < 24) ctrl[t] = 0;
    sm[t] = Gx[t] + Gx[t + 1024] + Gx[t + 2048] + Gx[t + 3072];
    __syncthreads();
    for (int m = 512; m >= 1; m >>= 1) {
        if (t < m) sm[t] += sm[t + m];
        __syncthreads();
    }
    if (t == 0) gsum[0] = sm[0];
}

__global__ __launch_bounds__(256) void k_topk(const float* __restrict__ logits,
                                              const float* __restrict__ Gx,
                                              const float* __restrict__ gsum,
                                              const float* __restrict__ gamma,
                                              const float* __restrict__ beta,
                                              int* __restrict__ tidx, float* __restrict__ tp,
                                              int* __restrict__ counts) {
    int b = blockIdx.x * 256 + threadIdx.x;
    float nx = Gx[b] / (gsum[0] * (1.0f / (float)B_SZ) + GEPS);
    float l[NE];
    float mx = -1e30f;
#pragma unroll
    for (int e = 0; e < NE; ++e) {
        l[e] = gamma[e] * (logits[b * NE + e] * nx) + beta[e];
        mx = fmaxf(mx, l[e]);
    }
    float se = 0.f;
#pragma unroll
    for (int e = 0; e < NE; ++e) { l[e] = expf(l[e] - mx); se += l[e]; }
    float inv = 1.f / se;
    int i0 = 0; float p0 = l[0];
#pragma unroll
    for (int e = 1; e < NE; ++e) if (l[e] > p0) { p0 = l[e]; i0 = e; }
    int i1 = -1; float p1 = -1.f;
#pragma unroll
    for (int e = 0; e < NE; ++e) if (e != i0 && l[e] > p1) { p1 = l[e]; i1 = e; }
    tidx[b * 2 + 0] = i0; tidx[b * 2 + 1] = i1;
    tp[b * 2 + 0] = p0 * inv; tp[b * 2 + 1] = p1 * inv;
    atomicAdd(&counts[i0], 1);
    atomicAdd(&counts[i1], 1);
}

__global__ void k_offsets(const int* __restrict__ counts, int* __restrict__ offs) {
    if (threadIdx.x == 0) {
        int a = 0;
        for (int e = 0; e < NE; ++e) { offs[e] = a; a += counts[e]; }
    }
}

__global__ __launch_bounds__(256) void k_fill(const int* __restrict__ tidx, const float* __restrict__ tp,
                                              const int* __restrict__ offs, int* __restrict__ cursors,
                                              int* __restrict__ rowsw, int* __restrict__ slotof) {
    int b = blockIdx.x * 256 + threadIdx.x;
#pragma unroll
    for (int k = 0; k < 2; ++k) {
        int e = tidx[b * 2 + k];
        int pos = atomicAdd(&cursors[e], 1);
        int at = offs[e] + pos;
        rowsw[at] = b * 2 + k;
        slotof[b * 2 + k] = at;
    }
}

// ====== 128x128 / BK=64, XOR-swizzled, double-buffered (round-6/10 proven) ======
// LDS buffer = [A 16KB | B 16KB]; buf0 @0, buf1 @32KB. LDS[r][slot] holds global
// chunk slot^(r&7); pre-swizzled source + swizzled ds_read (0 conflicts, r5-r10).

__device__ __forceinline__ void compute_bk64(const short* buf, const int* aoff, const int* boff,
                                             floatx4 acc[4][4]) {
    const short* sA = buf;
    const short* sB = buf + 8192;
    short8 a0[4], a1[4], b0[4], b1[4];
#pragma unroll
    for (int i = 0; i < 4; ++i) {
        a0[i] = *(const short8*)(sA + aoff[i]);
        a1[i] = *(const short8*)(sA + (aoff[i] ^ 32));
        b0[i] = *(const short8*)(sB + boff[i]);
        b1[i] = *(const short8*)(sB + (boff[i] ^ 32));
    }
    asm volatile("s_waitcnt lgkmcnt(0)" ::: "memory");
    __builtin_amdgcn_sched_barrier(0);
    __builtin_amdgcn_s_setprio(1);
#pragma unroll
    for (int i = 0; i < 4; ++i)
#pragma unroll
        for (int j = 0; j < 4; ++j) {
            acc[i][j] = __builtin_amdgcn_mfma_f32_16x16x32_bf16(a0[i], b0[j], acc[i][j], 0, 0, 0);
            acc[i][j] = __builtin_amdgcn_mfma_f32_16x16x32_bf16(a1[i], b1[j], acc[i][j], 0, 0, 0);
        }
    __builtin_amdgcn_s_setprio(0);
}

__device__ __forceinline__ void stage_bk64(const unsigned short* const* pa,
                                           const unsigned short* const* pb,
                                           char* bufc, int koff, int tid) {
#pragma unroll
    for (int c = 0; c < 4; ++c) {
        async16(pa[c] + koff, bufc + c * 4096 + tid * 16);
        async16(pb[c] + koff, bufc + 16384 + c * 4096 + tid * 16);
    }
}

__device__ __forceinline__ void core64db(const unsigned short* const* pa,
                                         const unsigned short* const* pb,
                                         short* smem, int nkt, int wm, int wn,
                                         int tid, int lane, floatx4 acc[4][4]) {
    char* b0c = (char*)smem;
    char* b1c = b0c + 32768;
    const int sl = ((lane >> 4) ^ (lane & 7)) * 8;
    int aoff[4], boff[4];
#pragma unroll
    for (int i = 0; i < 4; ++i) {
        aoff[i] = (wm * 64 + i * 16 + (lane & 15)) * 64 + sl;
        boff[i] = (wn * 64 + i * 16 + (lane & 15)) * 64 + sl;
    }
    stage_bk64(pa, pb, b0c, 0, tid);
    __syncthreads();
#pragma unroll 1
    for (int kt = 0; kt < nkt; kt += 2) {
        if (kt + 1 < nkt) stage_bk64(pa, pb, b1c, (kt + 1) * 64, tid);
        compute_bk64(smem, aoff, boff, acc);
        __syncthreads();
        if (kt + 2 < nkt) stage_bk64(pa, pb, b0c, (kt + 2) * 64, tid);
        compute_bk64(smem + 16384, aoff, boff, acc);
        __syncthreads();
    }
}

// GEMM1 + W2-conversion role-split (grid 5120 = 1024x5):
//   role = bid%5 in {0..3} -> h-GEMM tile hbid = (bid/5)*4+role  (4096 tiles, FULL)
//   role == 4              -> grid-strided W2 fp32->bf16 (1024 blocks, overlaps)
__global__ __launch_bounds__(256) void k_h8f(const unsigned short* __restrict__ xb,
                                             const unsigned short* __restrict__ w1b,
                                             const float* __restrict__ b1,
                                             unsigned short* __restrict__ hout,
                                             const float* __restrict__ W2,
                                             unsigned short* __restrict__ w2b) {
    const int bid = blockIdx.x;
    const int role = bid % 5;
    if (role == 4) {
        cvt_span(W2, w2b, NE * OUTE * HIDE, bid / 5, 1024);
        return;
    }
    const int hbid = (bid / 5) * 4 + role;           // 0..4095, bijective
    extern __shared__ short smem[];
    const int tid = threadIdx.x, lane = tid & 63, wid = tid >> 6;
    const int wm = wid >> 1, wn = wid & 1;
    const int wg = (hbid & 7) * 512 + (hbid >> 3);   // XCD swizzle over 4096
    const int mt = wg & 31, nt = wg >> 5;            // mt 0..31, nt 0..127
    const int m0 = mt * 128, n0 = nt * 128;
    const int srow = tid >> 3;
    const int cswz = ((tid & 7) ^ (srow & 7)) * 8;
    const unsigned short* pa[4];
    const unsigned short* pb[4];
#pragma unroll
    for (int c = 0; c < 4; ++c) {
        pa[c] = xb  + (size_t)(m0 + 32 * c + srow) * IN_SZ + cswz;
        pb[c] = w1b + (size_t)(n0 + 32 * c + srow) * IN_SZ + cswz;
    }
    floatx4 acc[4][4] = {};
    core64db(pa, pb, smem, IN_SZ / 64, wm, wn, tid, lane, acc);
#pragma unroll
    for (int i = 0; i < 4; ++i)
#pragma unroll
        for (int j = 0; j < 4; ++j)
#pragma unroll
            for (int r = 0; r < 4; ++r) {
                int row = m0 + wm * 64 + i * 16 + (lane >> 4) * 4 + r;
                int col = n0 + wn * 64 + j * 16 + (lane & 15);
                float v = acc[i][j][r] + b1[col];
                hout[(size_t)row * HIDE + col] = f2bf(fmaxf(v, 0.f));
            }
}

// GEMM2 grouped, split-K=2: gathered h rows x W2 expert slice -> bf16 partials
__global__ __launch_bounds__(256) void k_moe(const unsigned short* __restrict__ h,
                                             const unsigned short* __restrict__ w2b,
                                             const int* __restrict__ counts,
                                             const int* __restrict__ offs,
                                             const int* __restrict__ rowsw,
                                             unsigned short* __restrict__ parts) {
    // grid 4096 = 8e x 2sp x 8nt x 32mt; mt innermost -> same-XCD share B-panel
    const int wg = (blockIdx.x & 7) * (gridDim.x >> 3) + (blockIdx.x >> 3);
    const int mt = wg & 31, nt = (wg >> 5) & 7, sp = (wg >> 8) & 1, e = wg >> 9;
    const int gn = counts[e];
    if (mt * 128 >= gn) return;
    const int gbase = offs[e];
    extern __shared__ short smem[];
    const int tid = threadIdx.x, lane = tid & 63, wid = tid >> 6;
    const int wm = wid >> 1, wn = wid & 1;
    const int srow = tid >> 3;
    const int cswz = ((tid & 7) ^ (srow & 7)) * 8;
    const unsigned short* pa[4];
    const unsigned short* pb[4];
#pragma unroll
    for (int c = 0; c < 4; ++c) {
        int lr = mt * 128 + 32 * c + srow;
        if (lr > gn - 1) lr = gn - 1;
        int grow = rowsw[gbase + lr] >> 1;
        pa[c] = h + (size_t)grow * HIDE + sp * KSPL + cswz;
        pb[c] = w2b + (size_t)(e * OUTE + nt * 128 + 32 * c + srow) * HIDE + sp * KSPL + cswz;
    }
    floatx4 acc[4][4] = {};
    core64db(pa, pb, smem, KSPL / 64, wm, wn, tid, lane, acc);
    unsigned short* pbase = parts + (size_t)sp * B_SZ * 2 * OUTE;
#pragma unroll
    for (int i = 0; i < 4; ++i)
#pragma unroll
        for (int j = 0; j < 4; ++j)
#pragma unroll
            for (int r = 0; r < 4; ++r) {
                int lr = mt * 128 + wm * 64 + i * 16 + (lane >> 4) * 4 + r;
                if (lr < gn) {
                    int at = gbase + lr;
                    int col = nt * 128 + wn * 64 + j * 16 + (lane & 15);
                    pbase[(size_t)at * OUTE + col] = f2bf(acc[i][j][r]);
                }
            }
}

// reduce: ymix[b] = sum_k tp[b,k] * (sum_sp parts[sp][slot(b,k)] + b2[e_k])
__global__ __launch_bounds__(256) void k_reduce(const unsigned short* __restrict__ parts,
                                                const int* __restrict__ slotof,
                                                const int* __restrict__ tidx,
                                                const float* __restrict__ tp,
                                                const float* __restrict__ b2,
                                                unsigned short* __restrict__ ymix) {
    int i = blockIdx.x * 256 + threadIdx.x;   // B_SZ * 256 threads, 4 cols each
    int b = i >> 8, col = (i & 255) * 4;
    int at0 = slotof[b * 2], at1 = slotof[b * 2 + 1];
    int e0 = tidx[b * 2], e1 = tidx[b * 2 + 1];
    float q0 = tp[b * 2], q1 = tp[b * 2 + 1];
    float y0[4] = {0.f, 0.f, 0.f, 0.f}, y1[4] = {0.f, 0.f, 0.f, 0.f};
#pragma unroll
    for (int sp = 0; sp < NSPLIT; ++sp) {
        ushort4 u0 = *(const ushort4*)(parts + ((size_t)sp * B_SZ * 2 + at0) * OUTE + col);
        ushort4 u1 = *(const ushort4*)(parts + ((size_t)sp * B_SZ * 2 + at1) * OUTE + col);
        y0[0] += bf2f(u0.x); y0[1] += bf2f(u0.y); y0[2] += bf2f(u0.z); y0[3] += bf2f(u0.w);
        y1[0] += bf2f(u1.x); y1[1] += bf2f(u1.y); y1[2] += bf2f(u1.z); y1[3] += bf2f(u1.w);
    }
    float4 bb0 = *(const float4*)(b2 + (size_t)e0 * OUTE + col);
    float4 bb1 = *(const float4*)(b2 + (size_t)e1 * OUTE + col);
    ushort4 o;
    o.x = f2bf(q0 * (y0[0] + bb0.x) + q1 * (y1[0] + bb1.x));
    o.y = f2bf(q0 * (y0[1] + bb0.y) + q1 * (y1[1] + bb1.y));
    o.z = f2bf(q0 * (y0[2] + bb0.z) + q1 * (y1[2] + bb1.z));
    o.w = f2bf(q0 * (y0[3] + bb0.w) + q1 * (y1[3] + bb1.w));
    *(ushort4*)(ymix + (size_t)b * OUTE + col) = o;
}

// GEMM3: out = ymix @ Wc^T + bc  (r6 core, B rows clamped to NC)
__global__ __launch_bounds__(256) void k_gemm_out(const unsigned short* __restrict__ ymix,
                                                  const unsigned short* __restrict__ wcb,
                                                  const float* __restrict__ bc,
                                                  float* __restrict__ out) {
    const int mt = blockIdx.x >> 3, nt = blockIdx.x & 7;
    const int m0 = mt * 128, n0 = nt * 128;
    extern __shared__ short smem[];
    const int tid = threadIdx.x, lane = tid & 63, wid = tid >> 6;
    const int wm = wid >> 1, wn = wid & 1;
    const int srow = tid >> 3;
    const int cswz = ((tid & 7) ^ (srow & 7)) * 8;
    const unsigned short* pa[4];
    const unsigned short* pb[4];
#pragma unroll
    for (int c = 0; c < 4; ++c) {
        pa[c] = ymix + (size_t)(m0 + 32 * c + srow) * IN_SZ + cswz;
        int br = n0 + 32 * c + srow; if (br > NC - 1) br = NC - 1;
        pb[c] = wcb + (size_t)br * IN_SZ + cswz;
    }
    floatx4 acc[4][4] = {};
    core64db(pa, pb, smem, IN_SZ / 64, wm, wn, tid, lane, acc);
#pragma unroll
    for (int i = 0; i < 4; ++i)
#pragma unroll
        for (int j = 0; j < 4; ++j)
#pragma unroll
            for (int r = 0; r < 4; ++r) {
                int row = m0 + wm * 64 + i * 16 + (lane >> 4) * 4 + r;
                int col = n0 + wn * 64 + j * 16 + (lane & 15);
                if (col < NC)
                    out[(size_t)row * NC + col] = acc[i][j][r] + bc[col];
            }
}

extern "C" void kernel_launch(void* const* d_in, const int* in_sizes, int n_in,
                              void* d_out, int out_size, void* d_ws, size_t ws_size,
                              hipStream_t stream) {
    const float* x     = (const float*)d_in[0];
    const float* Wg    = (const float*)d_in[1];
    const float* bg    = (const float*)d_in[2];
    const float* gamma = (const float*)d_in[3];
    const float* beta  = (const float*)d_in[4];
    const float* W1    = (const float*)d_in[5];
    const float* b1    = (const float*)d_in[6];
    const float* W2    = (const float*)d_in[7];
    const float* b2    = (const float*)d_in[8];
    const float* Wc    = (const float*)d_in[9];
    const float* bc    = (const float*)d_in[10];
    float* out = (float*)d_out;

    char* ws = (char*)d_ws;
    size_t o = 0;
    auto carve = [&](size_t bytes) { char* p = ws + o; o += (bytes + 255) & ~(size_t)255; return p; };
    unsigned short* xb    = (unsigned short*)carve((size_t)B_SZ * IN_SZ * 2);
    unsigned short* w1b   = (unsigned short*)carve((size_t)HIDE * IN_SZ * 2);
    unsigned short* w2b   = (unsigned short*)carve((size_t)NE * OUTE * HIDE * 2);
    unsigned short* wcb   = (unsigned short*)carve((size_t)NC * IN_SZ * 2);
    unsigned short* h     = (unsigned short*)carve((size_t)B_SZ * HIDE * 2);
    unsigned short* parts = (unsigned short*)carve((size_t)NSPLIT * B_SZ * 2 * OUTE * 2);
    unsigned short* ymix  = (unsigned short*)carve((size_t)B_SZ * OUTE * 2);
    float* logits = (float*)carve((size_t)B_SZ * NE * 4);
    float* Gx     = (float*)carve((size_t)B_SZ * 4);
    int*   tidx   = (int*)carve((size_t)B_SZ * 2 * 4);
    float* tp     = (float*)carve((size_t)B_SZ * 2 * 4);
    int*   rowsw  = (int*)carve((size_t)B_SZ * 2 * 4);
    int*   slotof = (int*)carve((size_t)B_SZ * 2 * 4);
    int*   ctrl   = (int*)carve(256);
    int* counts  = ctrl;
    int* cursors = ctrl + 8;
    int* offs    = ctrl + 16;
    float* gsum  = (float*)(ctrl + 24);

    // 64KB dynamic LDS for the dbuf GEMM kernels (idempotent, not captured)
    hipFuncSetAttribute((const void*)k_h8f,      hipFuncAttributeMaxDynamicSharedMemorySize, 65536);
    hipFuncSetAttribute((const void*)k_moe,      hipFuncAttributeMaxDynamicSharedMemorySize, 65536);
    hipFuncSetAttribute((const void*)k_gemm_out, hipFuncAttributeMaxDynamicSharedMemorySize, 65536);

    // gating + W1/Wc conversion overlapped (1024 gate + 512 W1 + 64 Wc blocks)
    k_gatef<<<1600, 256, 0, stream>>>(x, Wg, bg, logits, Gx, xb, W1, w1b, Wc, wcb);
    k_gsum<<<1, 1024, 0, stream>>>(Gx, gsum, ctrl);
    k_topk<<<B_SZ / 256, 256, 0, stream>>>(logits, Gx, gsum, gamma, beta, tidx, tp, counts);
    k_offsets<<<1, 64, 0, stream>>>(counts, offs);
    k_fill<<<B_SZ / 256, 256, 0, stream>>>(tidx, tp, offs, cursors, rowsw, slotof);

    // h-GEMM (4096 tiles, FULL) + W2 conversion (1024 blocks), role-interleaved
    k_h8f<<<5120, 256, 65536, stream>>>(xb, w1b, b1, h, W2, w2b);
    k_moe<<<NE * 32 * 8 * NSPLIT, 256, 65536, stream>>>(h, w2b, counts, offs, rowsw, parts);
    k_reduce<<<B_SZ, 256, 0, stream>>>(parts, slotof, tidx, tp, b2, ymix);
    k_gemm_out<<<(B_SZ / 128) * 8, 256, 65536, stream>>>(ymix, wcb, bc, out);
}

// Round 13
// 881.470 us; speedup vs baseline: 1.5823x; 1.0190x over previous
//
#include <hip/hip_runtime.h>
#include <stdint.h>

#define B_SZ   4096
#define IN_SZ  1024
#define NE     8
#define NC     1000
#define HIDE   16384   // HID*E
#define OUTE   1024    // OUT per expert
#define GEPS   1e-6f
#define NSPLIT 2
#define KSPL   8192    // HIDE / NSPLIT

// W2 conversion spans (elements), distributed over the gating chain
#define W2TOT  134217728
#define SA     33554432   // k_gatef   (1024 cvt blocks)
#define SB     41943040   // k_gsumf   (2047 cvt blocks x 1024 thr)
#define SC     25165824   // k_topkf   (1024 cvt blocks)
#define SD     12582912   // k_offsetsf(511 cvt blocks)
#define SE     20971520   // k_fillf   (1008 cvt blocks)

typedef __attribute__((ext_vector_type(8))) short short8;
typedef __attribute__((ext_vector_type(4))) float floatx4;

__device__ __forceinline__ unsigned short f2bf(float f) {
    unsigned u = __float_as_uint(f);
    u += 0x7fffu + ((u >> 16) & 1u);
    return (unsigned short)(u >> 16);
}
__device__ __forceinline__ float bf2f(unsigned short h) {
    return __uint_as_float(((unsigned)h) << 16);
}

__device__ __forceinline__ void async16(const void* g, void* l) {
    __builtin_amdgcn_global_load_lds(
        (const __attribute__((address_space(1))) void*)g,
        (__attribute__((address_space(3))) void*)l, 16, 0, 0);
}

// 8-wide fp32->bf16 span conversion, grid-strided over nb blocks of blockDim
__device__ __forceinline__ void cvt_span(const float* __restrict__ src,
                                         unsigned short* __restrict__ dst,
                                         int n, int bid, int nb) {
    const int bdim = (int)blockDim.x;
    int i = (bid * bdim + (int)threadIdx.x) * 8;
    int stride = nb * bdim * 8;
    for (; i < n; i += stride) {
        float4 v0 = *(const float4*)(src + i);
        float4 v1 = *(const float4*)(src + i + 4);
        uint4 w;
        w.x = (unsigned)f2bf(v0.x) | ((unsigned)f2bf(v0.y) << 16);
        w.y = (unsigned)f2bf(v0.z) | ((unsigned)f2bf(v0.w) << 16);
        w.z = (unsigned)f2bf(v1.x) | ((unsigned)f2bf(v1.y) << 16);
        w.w = (unsigned)f2bf(v1.z) | ((unsigned)f2bf(v1.w) << 16);
        *(uint4*)(dst + i) = w;
    }
}

// ---- gating (fp32 exact) + bf16 x + W1/Wc cvt + W2 span A ---------------------
// [0,1024): gate; [1024,1536): W1; [1536,1600): Wc; [1600,2624): W2[0,SA)
__global__ __launch_bounds__(256) void k_gatef(const float* __restrict__ x,
                                               const float* __restrict__ Wg,
                                               const float* __restrict__ bg,
                                               float* __restrict__ logits,
                                               float* __restrict__ Gx,
                                               unsigned short* __restrict__ xb,
                                               const float* __restrict__ W1,
                                               unsigned short* __restrict__ w1b,
                                               const float* __restrict__ Wc,
                                               unsigned short* __restrict__ wcb,
                                               const float* __restrict__ W2,
                                               unsigned short* __restrict__ w2b) {
    const int bid = blockIdx.x;
    if (bid >= 1024) {
        if (bid < 1536)      cvt_span(W1, w1b, HIDE * IN_SZ, bid - 1024, 512);
        else if (bid < 1600) cvt_span(Wc, wcb, NC * IN_SZ,   bid - 1536, 64);
        else                 cvt_span(W2, w2b, SA,           bid - 1600, 1024);
        return;
    }
    int wid = threadIdx.x >> 6, lane = threadIdx.x & 63;
    int b = bid * 4 + wid;
    const float* xr = x + (size_t)b * IN_SZ;
    float xv[16];
#pragma unroll
    for (int t = 0; t < 16; ++t) xv[t] = xr[lane + 64 * t];
    unsigned short* xbr = xb + (size_t)b * IN_SZ;
#pragma unroll
    for (int t = 0; t < 16; ++t) xbr[lane + 64 * t] = f2bf(xv[t]);
    float lg[NE];
#pragma unroll
    for (int e = 0; e < NE; ++e) {
        const float* wr = Wg + e * IN_SZ;
        float s = 0.f;
#pragma unroll
        for (int t = 0; t < 16; ++t) s += xv[t] * wr[lane + 64 * t];
#pragma unroll
        for (int m = 32; m >= 1; m >>= 1) s += __shfl_xor(s, m, 64);
        lg[e] = s + bg[e];
    }
    if (lane == 0) {
        float ss = 0.f;
#pragma unroll
        for (int e = 0; e < NE; ++e) { logits[b * NE + e] = lg[e]; ss += lg[e] * lg[e]; }
        Gx[b] = sqrtf(ss);
    }
}

// block 0: batch-sum of Gx + zero ctrl; blocks 1..2047: W2 span B
__global__ __launch_bounds__(1024) void k_gsumf(const float* __restrict__ Gx,
                                                float* __restrict__ gsum, int* __restrict__ ctrl,
                                                const float* __restrict__ W2,
                                                unsigned short* __restrict__ w2b) {
    if (blockIdx.x > 0) {
        cvt_span(W2 + SA, w2b + SA, SB, blockIdx.x - 1, 2047);
        return;
    }
    __shared__ float sm[1024];
    int t = threadIdx.x;
    if (t < 24) ctrl[t] = 0;
    sm[t] = Gx[t] + Gx[t + 1024] + Gx[t + 2048] + Gx[t + 3072];
    __syncthreads();
    for (int m = 512; m >= 1; m >>= 1) {
        if (t < m) sm[t] += sm[t + m];
        __syncthreads();
    }
    if (t == 0) gsum[0] = sm[0];
}

// blocks 0..15: topk; 16..1039: W2 span C
__global__ __launch_bounds__(256) void k_topkf(const float* __restrict__ logits,
                                               const float* __restrict__ Gx,
                                               const float* __restrict__ gsum,
                                               const float* __restrict__ gamma,
                                               const float* __restrict__ beta,
                                               int* __restrict__ tidx, float* __restrict__ tp,
                                               int* __restrict__ counts,
                                               const float* __restrict__ W2,
                                               unsigned short* __restrict__ w2b) {
    if (blockIdx.x >= 16) {
        cvt_span(W2 + (SA + SB), w2b + (SA + SB), SC, blockIdx.x - 16, 1024);
        return;
    }
    int b = blockIdx.x * 256 + threadIdx.x;
    float nx = Gx[b] / (gsum[0] * (1.0f / (float)B_SZ) + GEPS);
    float l[NE];
    float mx = -1e30f;
#pragma unroll
    for (int e = 0; e < NE; ++e) {
        l[e] = gamma[e] * (logits[b * NE + e] * nx) + beta[e];
        mx = fmaxf(mx, l[e]);
    }
    float se = 0.f;
#pragma unroll
    for (int e = 0; e < NE; ++e) { l[e] = expf(l[e] - mx); se += l[e]; }
    float inv = 1.f / se;
    int i0 = 0; float p0 = l[0];
#pragma unroll
    for (int e = 1; e < NE; ++e) if (l[e] > p0) { p0 = l[e]; i0 = e; }
    int i1 = -1; float p1 = -1.f;
#pragma unroll
    for (int e = 0; e < NE; ++e) if (e != i0 && l[e] > p1) { p1 = l[e]; i1 = e; }
    tidx[b * 2 + 0] = i0; tidx[b * 2 + 1] = i1;
    tp[b * 2 + 0] = p0 * inv; tp[b * 2 + 1] = p1 * inv;
    atomicAdd(&counts[i0], 1);
    atomicAdd(&counts[i1], 1);
}

// block 0: offsets; blocks 1..511: W2 span D
__global__ __launch_bounds__(256) void k_offsetsf(const int* __restrict__ counts,
                                                  int* __restrict__ offs,
                                                  const float* __restrict__ W2,
                                                  unsigned short* __restrict__ w2b) {
    if (blockIdx.x > 0) {
        cvt_span(W2 + (SA + SB + SC), w2b + (SA + SB + SC), SD, blockIdx.x - 1, 511);
        return;
    }
    if (threadIdx.x == 0) {
        int a = 0;
        for (int e = 0; e < NE; ++e) { offs[e] = a; a += counts[e]; }
    }
}

// blocks 0..15: fill; 16..1023: W2 span E
__global__ __launch_bounds__(256) void k_fillf(const int* __restrict__ tidx, const float* __restrict__ tp,
                                               const int* __restrict__ offs, int* __restrict__ cursors,
                                               int* __restrict__ rowsw, int* __restrict__ slotof,
                                               const float* __restrict__ W2,
                                               unsigned short* __restrict__ w2b) {
    if (blockIdx.x >= 16) {
        cvt_span(W2 + (SA + SB + SC + SD), w2b + (SA + SB + SC + SD), SE, blockIdx.x - 16, 1008);
        return;
    }
    int b = blockIdx.x * 256 + threadIdx.x;
#pragma unroll
    for (int k = 0; k < 2; ++k) {
        int e = tidx[b * 2 + k];
        int pos = atomicAdd(&cursors[e], 1);
        int at = offs[e] + pos;
        rowsw[at] = b * 2 + k;
        slotof[b * 2 + k] = at;
    }
}

// ====== 128x128 / BK=64, XOR-swizzled, double-buffered (round-6/10 proven) ======
// LDS buffer = [A 16KB | B 16KB]; buf0 @0, buf1 @32KB. LDS[r][slot] holds global
// chunk slot^(r&7); pre-swizzled source + swizzled ds_read (0 conflicts, r5-r12).

__device__ __forceinline__ void compute_bk64(const short* buf, const int* aoff, const int* boff,
                                             floatx4 acc[4][4]) {
    const short* sA = buf;
    const short* sB = buf + 8192;
    short8 a0[4], a1[4], b0[4], b1[4];
#pragma unroll
    for (int i = 0; i < 4; ++i) {
        a0[i] = *(const short8*)(sA + aoff[i]);
        a1[i] = *(const short8*)(sA + (aoff[i] ^ 32));
        b0[i] = *(const short8*)(sB + boff[i]);
        b1[i] = *(const short8*)(sB + (boff[i] ^ 32));
    }
    asm volatile("s_waitcnt lgkmcnt(0)" ::: "memory");
    __builtin_amdgcn_sched_barrier(0);
    __builtin_amdgcn_s_setprio(1);
#pragma unroll
    for (int i = 0; i < 4; ++i)
#pragma unroll
        for (int j = 0; j < 4; ++j) {
            acc[i][j] = __builtin_amdgcn_mfma_f32_16x16x32_bf16(a0[i], b0[j], acc[i][j], 0, 0, 0);
            acc[i][j] = __builtin_amdgcn_mfma_f32_16x16x32_bf16(a1[i], b1[j], acc[i][j], 0, 0, 0);
        }
    __builtin_amdgcn_s_setprio(0);
}

__device__ __forceinline__ void stage_bk64(const unsigned short* const* pa,
                                           const unsigned short* const* pb,
                                           char* bufc, int koff, int tid) {
#pragma unroll
    for (int c = 0; c < 4; ++c) {
        async16(pa[c] + koff, bufc + c * 4096 + tid * 16);
        async16(pb[c] + koff, bufc + 16384 + c * 4096 + tid * 16);
    }
}

__device__ __forceinline__ void core64db(const unsigned short* const* pa,
                                         const unsigned short* const* pb,
                                         short* smem, int nkt, int wm, int wn,
                                         int tid, int lane, floatx4 acc[4][4]) {
    char* b0c = (char*)smem;
    char* b1c = b0c + 32768;
    const int sl = ((lane >> 4) ^ (lane & 7)) * 8;
    int aoff[4], boff[4];
#pragma unroll
    for (int i = 0; i < 4; ++i) {
        aoff[i] = (wm * 64 + i * 16 + (lane & 15)) * 64 + sl;
        boff[i] = (wn * 64 + i * 16 + (lane & 15)) * 64 + sl;
    }
    stage_bk64(pa, pb, b0c, 0, tid);
    __syncthreads();
#pragma unroll 1
    for (int kt = 0; kt < nkt; kt += 2) {
        if (kt + 1 < nkt) stage_bk64(pa, pb, b1c, (kt + 1) * 64, tid);
        compute_bk64(smem, aoff, boff, acc);
        __syncthreads();
        if (kt + 2 < nkt) stage_bk64(pa, pb, b0c, (kt + 2) * 64, tid);
        compute_bk64(smem + 16384, aoff, boff, acc);
        __syncthreads();
    }
}

// GEMM1: h = relu(x @ W1^T + b1)  — pure, 4096 tiles (r10-identical)
__global__ __launch_bounds__(256) void k_h8(const unsigned short* __restrict__ xb,
                                            const unsigned short* __restrict__ w1b,
                                            const float* __restrict__ b1,
                                            unsigned short* __restrict__ hout) {
    extern __shared__ short smem[];
    const int tid = threadIdx.x, lane = tid & 63, wid = tid >> 6;
    const int wm = wid >> 1, wn = wid & 1;
    const int wg = (blockIdx.x & 7) * (gridDim.x >> 3) + (blockIdx.x >> 3);
    const int mt = wg & 31, nt = wg >> 5;
    const int m0 = mt * 128, n0 = nt * 128;
    const int srow = tid >> 3;
    const int cswz = ((tid & 7) ^ (srow & 7)) * 8;
    const unsigned short* pa[4];
    const unsigned short* pb[4];
#pragma unroll
    for (int c = 0; c < 4; ++c) {
        pa[c] = xb  + (size_t)(m0 + 32 * c + srow) * IN_SZ + cswz;
        pb[c] = w1b + (size_t)(n0 + 32 * c + srow) * IN_SZ + cswz;
    }
    floatx4 acc[4][4] = {};
    core64db(pa, pb, smem, IN_SZ / 64, wm, wn, tid, lane, acc);
#pragma unroll
    for (int i = 0; i < 4; ++i)
#pragma unroll
        for (int j = 0; j < 4; ++j)
#pragma unroll
            for (int r = 0; r < 4; ++r) {
                int row = m0 + wm * 64 + i * 16 + (lane >> 4) * 4 + r;
                int col = n0 + wn * 64 + j * 16 + (lane & 15);
                float v = acc[i][j][r] + b1[col];
                hout[(size_t)row * HIDE + col] = f2bf(fmaxf(v, 0.f));
            }
}

// GEMM2 grouped, split-K=2: gathered h rows x W2 expert slice -> bf16 partials
__global__ __launch_bounds__(256) void k_moe(const unsigned short* __restrict__ h,
                                             const unsigned short* __restrict__ w2b,
                                             const int* __restrict__ counts,
                                             const int* __restrict__ offs,
                                             const int* __restrict__ rowsw,
                                             unsigned short* __restrict__ parts) {
    // grid 4096 = 8e x 2sp x 8nt x 32mt; mt innermost -> same-XCD share B-panel
    const int wg = (blockIdx.x & 7) * (gridDim.x >> 3) + (blockIdx.x >> 3);
    const int mt = wg & 31, nt = (wg >> 5) & 7, sp = (wg >> 8) & 1, e = wg >> 9;
    const int gn = counts[e];
    if (mt * 128 >= gn) return;
    const int gbase = offs[e];
    extern __shared__ short smem[];
    const int tid = threadIdx.x, lane = tid & 63, wid = tid >> 6;
    const int wm = wid >> 1, wn = wid & 1;
    const int srow = tid >> 3;
    const int cswz = ((tid & 7) ^ (srow & 7)) * 8;
    const unsigned short* pa[4];
    const unsigned short* pb[4];
#pragma unroll
    for (int c = 0; c < 4; ++c) {
        int lr = mt * 128 + 32 * c + srow;
        if (lr > gn - 1) lr = gn - 1;
        int grow = rowsw[gbase + lr] >> 1;
        pa[c] = h + (size_t)grow * HIDE + sp * KSPL + cswz;
        pb[c] = w2b + (size_t)(e * OUTE + nt * 128 + 32 * c + srow) * HIDE + sp * KSPL + cswz;
    }
    floatx4 acc[4][4] = {};
    core64db(pa, pb, smem, KSPL / 64, wm, wn, tid, lane, acc);
    unsigned short* pbase = parts + (size_t)sp * B_SZ * 2 * OUTE;
#pragma unroll
    for (int i = 0; i < 4; ++i)
#pragma unroll
        for (int j = 0; j < 4; ++j)
#pragma unroll
            for (int r = 0; r < 4; ++r) {
                int lr = mt * 128 + wm * 64 + i * 16 + (lane >> 4) * 4 + r;
                if (lr < gn) {
                    int at = gbase + lr;
                    int col = nt * 128 + wn * 64 + j * 16 + (lane & 15);
                    pbase[(size_t)at * OUTE + col] = f2bf(acc[i][j][r]);
                }
            }
}

// reduce: ymix[b] = sum_k tp[b,k] * (sum_sp parts[sp][slot(b,k)] + b2[e_k])
__global__ __launch_bounds__(256) void k_reduce(const unsigned short* __restrict__ parts,
                                                const int* __restrict__ slotof,
                                                const int* __restrict__ tidx,
                                                const float* __restrict__ tp,
                                                const float* __restrict__ b2,
                                                unsigned short* __restrict__ ymix) {
    int i = blockIdx.x * 256 + threadIdx.x;
    int b = i >> 8, col = (i & 255) * 4;
    int at0 = slotof[b * 2], at1 = slotof[b * 2 + 1];
    int e0 = tidx[b * 2], e1 = tidx[b * 2 + 1];
    float q0 = tp[b * 2], q1 = tp[b * 2 + 1];
    float y0[4] = {0.f, 0.f, 0.f, 0.f}, y1[4] = {0.f, 0.f, 0.f, 0.f};
#pragma unroll
    for (int sp = 0; sp < NSPLIT; ++sp) {
        ushort4 u0 = *(const ushort4*)(parts + ((size_t)sp * B_SZ * 2 + at0) * OUTE + col);
        ushort4 u1 = *(const ushort4*)(parts + ((size_t)sp * B_SZ * 2 + at1) * OUTE + col);
        y0[0] += bf2f(u0.x); y0[1] += bf2f(u0.y); y0[2] += bf2f(u0.z); y0[3] += bf2f(u0.w);
        y1[0] += bf2f(u1.x); y1[1] += bf2f(u1.y); y1[2] += bf2f(u1.z); y1[3] += bf2f(u1.w);
    }
    float4 bb0 = *(const float4*)(b2 + (size_t)e0 * OUTE + col);
    float4 bb1 = *(const float4*)(b2 + (size_t)e1 * OUTE + col);
    ushort4 o;
    o.x = f2bf(q0 * (y0[0] + bb0.x) + q1 * (y1[0] + bb1.x));
    o.y = f2bf(q0 * (y0[1] + bb0.y) + q1 * (y1[1] + bb1.y));
    o.z = f2bf(q0 * (y0[2] + bb0.z) + q1 * (y1[2] + bb1.z));
    o.w = f2bf(q0 * (y0[3] + bb0.w) + q1 * (y1[3] + bb1.w));
    *(ushort4*)(ymix + (size_t)b * OUTE + col) = o;
}

// GEMM3: out = ymix @ Wc^T + bc  (r6 core, B rows clamped to NC)
__global__ __launch_bounds__(256) void k_gemm_out(const unsigned short* __restrict__ ymix,
                                                  const unsigned short* __restrict__ wcb,
                                                  const float* __restrict__ bc,
                                                  float* __restrict__ out) {
    const int mt = blockIdx.x >> 3, nt = blockIdx.x & 7;
    const int m0 = mt * 128, n0 = nt * 128;
    extern __shared__ short smem[];
    const int tid = threadIdx.x, lane = tid & 63, wid = tid >> 6;
    const int wm = wid >> 1, wn = wid & 1;
    const int srow = tid >> 3;
    const int cswz = ((tid & 7) ^ (srow & 7)) * 8;
    const unsigned short* pa[4];
    const unsigned short* pb[4];
#pragma unroll
    for (int c = 0; c < 4; ++c) {
        pa[c] = ymix + (size_t)(m0 + 32 * c + srow) * IN_SZ + cswz;
        int br = n0 + 32 * c + srow; if (br > NC - 1) br = NC - 1;
        pb[c] = wcb + (size_t)br * IN_SZ + cswz;
    }
    floatx4 acc[4][4] = {};
    core64db(pa, pb, smem, IN_SZ / 64, wm, wn, tid, lane, acc);
#pragma unroll
    for (int i = 0; i < 4; ++i)
#pragma unroll
        for (int j = 0; j < 4; ++j)
#pragma unroll
            for (int r = 0; r < 4; ++r) {
                int row = m0 + wm * 64 + i * 16 + (lane >> 4) * 4 + r;
                int col = n0 + wn * 64 + j * 16 + (lane & 15);
                if (col < NC)
                    out[(size_t)row * NC + col] = acc[i][j][r] + bc[col];
            }
}

extern "C" void kernel_launch(void* const* d_in, const int* in_sizes, int n_in,
                              void* d_out, int out_size, void* d_ws, size_t ws_size,
                              hipStream_t stream) {
    const float* x     = (const float*)d_in[0];
    const float* Wg    = (const float*)d_in[1];
    const float* bg    = (const float*)d_in[2];
    const float* gamma = (const float*)d_in[3];
    const float* beta  = (const float*)d_in[4];
    const float* W1    = (const float*)d_in[5];
    const float* b1    = (const float*)d_in[6];
    const float* W2    = (const float*)d_in[7];
    const float* b2    = (const float*)d_in[8];
    const float* Wc    = (const float*)d_in[9];
    const float* bc    = (const float*)d_in[10];
    float* out = (float*)d_out;

    char* ws = (char*)d_ws;
    size_t o = 0;
    auto carve = [&](size_t bytes) { char* p = ws + o; o += (bytes + 255) & ~(size_t)255; return p; };
    unsigned short* xb    = (unsigned short*)carve((size_t)B_SZ * IN_SZ * 2);
    unsigned short* w1b   = (unsigned short*)carve((size_t)HIDE * IN_SZ * 2);
    unsigned short* w2b   = (unsigned short*)carve((size_t)NE * OUTE * HIDE * 2);
    unsigned short* wcb   = (unsigned short*)carve((size_t)NC * IN_SZ * 2);
    unsigned short* h     = (unsigned short*)carve((size_t)B_SZ * HIDE * 2);
    unsigned short* parts = (unsigned short*)carve((size_t)NSPLIT * B_SZ * 2 * OUTE * 2);
    unsigned short* ymix  = (unsigned short*)carve((size_t)B_SZ * OUTE * 2);
    float* logits = (float*)carve((size_t)B_SZ * NE * 4);
    float* Gx     = (float*)carve((size_t)B_SZ * 4);
    int*   tidx   = (int*)carve((size_t)B_SZ * 2 * 4);
    float* tp     = (float*)carve((size_t)B_SZ * 2 * 4);
    int*   rowsw  = (int*)carve((size_t)B_SZ * 2 * 4);
    int*   slotof = (int*)carve((size_t)B_SZ * 2 * 4);
    int*   ctrl   = (int*)carve(256);
    int* counts  = ctrl;
    int* cursors = ctrl + 8;
    int* offs    = ctrl + 16;
    float* gsum  = (float*)(ctrl + 24);

    // 64KB dynamic LDS for the dbuf GEMM kernels (idempotent, not captured)
    hipFuncSetAttribute((const void*)k_h8,       hipFuncAttributeMaxDynamicSharedMemorySize, 65536);
    hipFuncSetAttribute((const void*)k_moe,      hipFuncAttributeMaxDynamicSharedMemorySize, 65536);
    hipFuncSetAttribute((const void*)k_gemm_out, hipFuncAttributeMaxDynamicSharedMemorySize, 65536);

    // gating chain, each kernel carrying a disjoint slice of the W2 conversion
    k_gatef<<<2624, 256, 0, stream>>>(x, Wg, bg, logits, Gx, xb, W1, w1b, Wc, wcb, W2, w2b);
    k_gsumf<<<2048, 1024, 0, stream>>>(Gx, gsum, ctrl, W2, w2b);
    k_topkf<<<1040, 256, 0, stream>>>(logits, Gx, gsum, gamma, beta, tidx, tp, counts, W2, w2b);
    k_offsetsf<<<512, 256, 0, stream>>>(counts, offs, W2, w2b);
    k_fillf<<<1024, 256, 0, stream>>>(tidx, tp, offs, cursors, rowsw, slotof, W2, w2b);

    // pure GEMMs (2 blocks/CU pairing restored for h8)
    k_h8<<<(B_SZ / 128) * (HIDE / 128), 256, 65536, stream>>>(xb, w1b, b1, h);
    k_moe<<<NE * 32 * 8 * NSPLIT, 256, 65536, stream>>>(h, w2b, counts, offs, rowsw, parts);
    k_reduce<<<B_SZ, 256, 0, stream>>>(parts, slotof, tidx, tp, b2, ymix);
    k_gemm_out<<<(B_SZ / 128) * 8, 256, 65536, stream>>>(ymix, wcb, bc, out);
}